// Round 1
// baseline (3720.263 us; speedup 1.0000x reference)
//
#include <hip/hip_runtime.h>
#include <hip/hip_bf16.h>
#include <math.h>

// Problem constants
#define BB   800
#define CIN  4
#define LIN  600
#define COUT 320
#define KW   26
#define LCONV 575            // 600-26+1
#define TT   45
#define POOLW 13
#define HID  160
#define LSTM_N 1280          // 2 dirs * 4 gates * 160, interleaved [dir][j][gate]
#define LSTM_K 320
#define LSTM_M 36000         // T*B
#define GENE_K 19795
#define GENE_N 320
#define LIN_K 14400
#define LIN_N 925

// Workspace layout (floats)
#define OFF_SEQ    ((size_t)0)          // [45][800][320] ; reused as weighted [800][14400]
#define OFF_H      ((size_t)11520000)   // [45][800][320]
#define OFF_BMAT   ((size_t)23040000)   // [1280][320]
#define OFF_BIAS   ((size_t)23449600)   // [1280]
#define OFF_GPART  ((size_t)23450880)   // [8][800][320]
#define OFF_GENE   ((size_t)25498880)   // [800][320]
#define OFF_STATS  ((size_t)25754880)   // [640] mean|invstd
#define OFF_ATTN   ((size_t)25755520)   // [45][800]
#define OFF_LPART  ((size_t)25791520)   // [4][800][925]
#define OFF_HID    ((size_t)28751520)   // [800][925]

__device__ __forceinline__ float sigf(float x) { return 1.0f / (1.0f + expf(-x)); }

// ---------------------------------------------------------------------------
// Build interleaved LSTM weight matrix Bmat[n][k], n = dir*640 + j*4 + gate,
// and fused bias vector bias[n] = b_ih + b_hh.
// ---------------------------------------------------------------------------
__global__ void prep_lstm_kernel(const float* __restrict__ wf, const float* __restrict__ bif,
                                 const float* __restrict__ bhf,
                                 const float* __restrict__ wb, const float* __restrict__ bib,
                                 const float* __restrict__ bhb,
                                 float* __restrict__ Bmat, float* __restrict__ biasv) {
    int idx = blockIdx.x * 256 + threadIdx.x;
    if (idx < LSTM_N * LSTM_K) {
        int n = idx / LSTM_K, k = idx % LSTM_K;
        int dir = n / 640, rr = n % 640;
        int j = rr >> 2, g = rr & 3;
        int srow = g * HID + j;
        const float* w = dir ? wb : wf;
        Bmat[idx] = w[srow * LSTM_K + k];
    }
    if (idx < LSTM_N) {
        int n = idx;
        int dir = n / 640, rr = n % 640;
        int j = rr >> 2, g = rr & 3;
        int srow = g * HID + j;
        biasv[n] = dir ? (bib[srow] + bhb[srow]) : (bif[srow] + bhf[srow]);
    }
}

// ---------------------------------------------------------------------------
// Fused Conv1d + ReLU + left-pad(14) + MaxPool(13) -> seq[t][b][c]
// One block per batch element. Weights (133KB) + x window (~5KB) in LDS.
// Two t-phases so the x slice fits beside the weights.
// ---------------------------------------------------------------------------
__global__ __launch_bounds__(512) void conv_pool_kernel(const float* __restrict__ x,
                                                        const float* __restrict__ cw,
                                                        const float* __restrict__ cb,
                                                        float* __restrict__ seq) {
    __shared__ float wlds[COUT * CIN * KW];   // 33280 floats
    __shared__ float xs[CIN][312];
    int b = blockIdx.x;
    int tid = threadIdx.x;
    for (int i = tid; i < COUT * CIN * KW; i += 512) wlds[i] = cw[i];

    for (int ph = 0; ph < 2; ++ph) {
        int t0 = ph ? 23 : 0;
        int t1 = ph ? 45 : 23;
        int xstart = ph ? 285 : 0;
        int xlen = ph ? 311 : 310;
        __syncthreads();   // protect wlds (ph0) / xs reuse (ph1)
        for (int i = tid; i < CIN * xlen; i += 512) {
            int ch = i / xlen, l = i % xlen;
            xs[ch][l] = x[((size_t)b * CIN + ch) * LIN + xstart + l];
        }
        __syncthreads();
        int nt = t1 - t0;
        int npairs = COUT * nt;
        for (int idx = tid; idx < npairs; idx += 512) {
            int c = idx / nt;
            int t = t0 + idx % nt;
            int base = t * POOLW - 14;     // conv-output index of pool-window start
            int xbase = base - xstart;     // index into xs
            float bias_c = cb[c];
            float accv[13];
#pragma unroll
            for (int j = 0; j < 13; ++j) accv[j] = bias_c;
#pragma unroll
            for (int ch = 0; ch < CIN; ++ch) {
                float xw[38];
#pragma unroll
                for (int ii = 0; ii < 38; ++ii) {
                    int xi = xbase + ii;
                    xw[ii] = (xi >= 0 && xi < xlen) ? xs[ch][xi] : 0.0f;
                }
#pragma unroll
                for (int k = 0; k < KW; ++k) {
                    float wv = wlds[c * (CIN * KW) + ch * KW + k];
#pragma unroll
                    for (int j = 0; j < 13; ++j) accv[j] = fmaf(xw[j + k], wv, accv[j]);
                }
            }
            float mx = 0.0f;   // pad positions / relu floor
#pragma unroll
            for (int j = 0; j < 13; ++j) {
                if (base + j >= 0) mx = fmaxf(mx, accv[j]);
            }
            seq[((size_t)t * BB + b) * COUT + c] = mx;
        }
    }
}

// ---------------------------------------------------------------------------
// Tiled GEMM  out[r][n] = sum_k A[r][k] * Bm[n][k]
// 64x64 tile, K-chunk 80, 256 threads, 4x4 accumulators.
// MODE 0: write split-K partial [s][M][N].
// MODE 1: LSTM epilogue (thread owns the 4 gates of one (dir,j)), writes h.
// ---------------------------------------------------------------------------
template <int MODE>
__global__ __launch_bounds__(256) void gemm_nt_kernel(const float* __restrict__ A, int lda,
                                                      const float* __restrict__ Bm, int ldb,
                                                      int M, int N, int K, int splitLen,
                                                      float* __restrict__ outp,
                                                      const float* __restrict__ biasv,
                                                      float* __restrict__ hout) {
    __shared__ alignas(16) float As[64][84];
    __shared__ alignas(16) float Bs[64][84];
    int bm = blockIdx.x, bn = blockIdx.y, s = blockIdx.z;
    int row0 = bm * 64, col0 = bn * 64;
    int kbeg = s * splitLen;
    int kend = min(K, kbeg + splitLen);
    int tid = threadIdx.x;
    int tr = tid >> 4, tc = tid & 15;

    float acc[4][4] = {};

    for (int k0 = kbeg; k0 < kend; k0 += 80) {
        int klen = kend - k0;
        if (klen > 80) klen = 80;
        for (int li = tid; li < 64 * 80; li += 256) {
            int r = li / 80, k = li % 80;
            int gr = row0 + r;
            As[r][k] = (gr < M && k < klen) ? A[(size_t)gr * lda + k0 + k] : 0.0f;
        }
        for (int li = tid; li < 64 * 80; li += 256) {
            int r = li / 80, k = li % 80;
            int gc = col0 + r;
            Bs[r][k] = (gc < N && k < klen) ? Bm[(size_t)gc * ldb + k0 + k] : 0.0f;
        }
        __syncthreads();
        for (int kk = 0; kk < 20; ++kk) {
            float4 a[4], bv[4];
#pragma unroll
            for (int i = 0; i < 4; ++i)
                a[i] = *reinterpret_cast<const float4*>(&As[tr * 4 + i][kk * 4]);
#pragma unroll
            for (int j = 0; j < 4; ++j)
                bv[j] = *reinterpret_cast<const float4*>(&Bs[tc * 4 + j][kk * 4]);
#pragma unroll
            for (int i = 0; i < 4; ++i)
#pragma unroll
                for (int j = 0; j < 4; ++j) {
                    acc[i][j] = fmaf(a[i].x, bv[j].x, acc[i][j]);
                    acc[i][j] = fmaf(a[i].y, bv[j].y, acc[i][j]);
                    acc[i][j] = fmaf(a[i].z, bv[j].z, acc[i][j]);
                    acc[i][j] = fmaf(a[i].w, bv[j].w, acc[i][j]);
                }
        }
        __syncthreads();
    }

    if (MODE == 0) {
#pragma unroll
        for (int i = 0; i < 4; ++i) {
            int gr = row0 + tr * 4 + i;
            if (gr >= M) continue;
#pragma unroll
            for (int j = 0; j < 4; ++j) {
                int gc = col0 + tc * 4 + j;
                if (gc < N) outp[((size_t)s * M + gr) * N + gc] = acc[i][j];
            }
        }
    } else {
        // LSTM: cols are [i,f,g,o] of one (dir, j). c0 = sig(i)*tanh(g); h = sig(o)*tanh(c0)
        int n0 = col0 + tc * 4;
        int dir = n0 / 640;
        int jj = (n0 % 640) >> 2;
        float bi = biasv[n0 + 0];
        float bg = biasv[n0 + 2];
        float bo = biasv[n0 + 3];
#pragma unroll
        for (int i = 0; i < 4; ++i) {
            int gr = row0 + tr * 4 + i;
            if (gr >= M) continue;
            float gi = acc[i][0] + bi;
            float gg = acc[i][2] + bg;
            float go = acc[i][3] + bo;
            float cc = sigf(gi) * tanhf(gg);
            float hv = sigf(go) * tanhf(cc);
            hout[(size_t)gr * 320 + dir * HID + jj] = hv;
        }
    }
}

// ---------------------------------------------------------------------------
// gene partial reduce + bias
// ---------------------------------------------------------------------------
__global__ void gene_reduce_kernel(const float* __restrict__ part, const float* __restrict__ gene_b,
                                   float* __restrict__ out) {
    int idx = blockIdx.x * 256 + threadIdx.x;
    if (idx >= BB * GENE_N) return;
    int n = idx % GENE_N;
    float sum = gene_b[n];
#pragma unroll
    for (int ss = 0; ss < 8; ++ss) sum += part[(size_t)ss * (BB * GENE_N) + idx];
    out[idx] = sum;
}

__global__ void bn_stats_kernel(const float* __restrict__ g, float* __restrict__ stats) {
    int n = blockIdx.x;
    int tid = threadIdx.x;
    float s = 0.0f, s2 = 0.0f;
    for (int m = tid; m < BB; m += 256) {
        float v = g[(size_t)m * GENE_N + n];
        s += v;
        s2 += v * v;
    }
    __shared__ float red0[256], red1[256];
    red0[tid] = s; red1[tid] = s2;
    __syncthreads();
    for (int off = 128; off; off >>= 1) {
        if (tid < off) { red0[tid] += red0[tid + off]; red1[tid] += red1[tid + off]; }
        __syncthreads();
    }
    if (tid == 0) {
        float mean = red0[0] / (float)BB;
        float var = red1[0] / (float)BB - mean * mean;
        stats[n] = mean;
        stats[GENE_N + n] = rsqrtf(var + 1e-5f);
    }
}

__global__ void bn_apply_kernel(float* __restrict__ g, const float* __restrict__ stats,
                                const float* __restrict__ gamma, const float* __restrict__ beta) {
    int idx = blockIdx.x * 256 + threadIdx.x;
    if (idx >= BB * GENE_N) return;
    int n = idx % GENE_N;
    float v = (g[idx] - stats[n]) * stats[GENE_N + n] * gamma[n] + beta[n];
    g[idx] = fmaxf(v, 0.0f);
}

// ---------------------------------------------------------------------------
// attn[t][b] = dot(h[t][b][:], gene[b][:])   (one wave per row)
// ---------------------------------------------------------------------------
__global__ void attn_kernel(const float* __restrict__ h, const float* __restrict__ gene,
                            float* __restrict__ attn) {
    int r = blockIdx.x;             // r = t*800 + b
    int b = r % BB;
    int lane = threadIdx.x;
    const float* hr = h + (size_t)r * 320;
    const float* gr = gene + (size_t)b * 320;
    float s = 0.0f;
    for (int d = lane; d < 320; d += 64) s += hr[d] * gr[d];
    for (int off = 32; off; off >>= 1) s += __shfl_down(s, off);
    if (lane == 0) attn[r] = s;
}

// weighted[b][t*320+d] = attn[t][b] * h[t][b][d]
__global__ void weighted_kernel(const float* __restrict__ h, const float* __restrict__ attn,
                                float* __restrict__ wout) {
    int idx = blockIdx.x * 256 + threadIdx.x;
    if (idx >= BB * TT * 320) return;
    int b = idx / (TT * 320);
    int rem = idx % (TT * 320);
    int t = rem / 320;
    int d = rem % 320;
    int r = t * BB + b;
    wout[idx] = attn[r] * h[(size_t)r * 320 + d];
}

__global__ void lin_reduce_kernel(const float* __restrict__ part, const float* __restrict__ lin_b,
                                  float* __restrict__ hid) {
    int idx = blockIdx.x * 256 + threadIdx.x;
    if (idx >= BB * LIN_N) return;
    int n = idx % LIN_N;
    float sum = lin_b[n];
#pragma unroll
    for (int ss = 0; ss < 4; ++ss) sum += part[(size_t)ss * (BB * LIN_N) + idx];
    hid[idx] = fmaxf(sum, 0.0f);
}

__global__ void out_kernel(const float* __restrict__ hid, const float* __restrict__ ow,
                           const float* __restrict__ ob, float* __restrict__ out) {
    int b = blockIdx.x;
    int lane = threadIdx.x;
    float s = 0.0f;
    for (int n = lane; n < LIN_N; n += 64) s += hid[(size_t)b * LIN_N + n] * ow[n];
    for (int off = 32; off; off >>= 1) s += __shfl_down(s, off);
    if (lane == 0) out[b] = s + ob[0];
}

// ---------------------------------------------------------------------------
extern "C" void kernel_launch(void* const* d_in, const int* in_sizes, int n_in,
                              void* d_out, int out_size, void* d_ws, size_t ws_size,
                              hipStream_t stream) {
    const float* x        = (const float*)d_in[0];
    const float* geneexpr = (const float*)d_in[1];
    const float* conv_w   = (const float*)d_in[2];
    const float* conv_b   = (const float*)d_in[3];
    const float* w_ih_f   = (const float*)d_in[4];
    const float* b_ih_f   = (const float*)d_in[5];
    const float* b_hh_f   = (const float*)d_in[6];
    const float* w_ih_b   = (const float*)d_in[7];
    const float* b_ih_b   = (const float*)d_in[8];
    const float* b_hh_b   = (const float*)d_in[9];
    const float* gene_w   = (const float*)d_in[10];
    const float* gene_b   = (const float*)d_in[11];
    const float* bn_gamma = (const float*)d_in[12];
    const float* bn_beta  = (const float*)d_in[13];
    const float* lin_w    = (const float*)d_in[14];
    const float* lin_b    = (const float*)d_in[15];
    const float* out_w    = (const float*)d_in[16];
    const float* out_b    = (const float*)d_in[17];

    float* ws  = (float*)d_ws;
    float* out = (float*)d_out;

    float* seq      = ws + OFF_SEQ;
    float* h        = ws + OFF_H;
    float* Bmat     = ws + OFF_BMAT;
    float* biasv    = ws + OFF_BIAS;
    float* gpart    = ws + OFF_GPART;
    float* gene     = ws + OFF_GENE;
    float* stats    = ws + OFF_STATS;
    float* attn     = ws + OFF_ATTN;
    float* weighted = ws + OFF_SEQ;     // reuse seq after LSTM
    float* lpart    = ws + OFF_LPART;
    float* hid      = ws + OFF_HID;

    // 1. interleaved LSTM weights + bias
    prep_lstm_kernel<<<1600, 256, 0, stream>>>(w_ih_f, b_ih_f, b_hh_f,
                                               w_ih_b, b_ih_b, b_hh_b, Bmat, biasv);
    // 2. conv + relu + pad + maxpool -> seq[t][b][c]
    conv_pool_kernel<<<BB, 512, 0, stream>>>(x, conv_w, conv_b, seq);
    // 3. LSTM gates GEMM + activation epilogue -> h[t][b][320]
    gemm_nt_kernel<1><<<dim3(563, 20, 1), 256, 0, stream>>>(seq, LSTM_K, Bmat, LSTM_K,
                                                            LSTM_M, LSTM_N, LSTM_K, LSTM_K,
                                                            nullptr, biasv, h);
    // 4. gene GEMM (split-K 8) -> partials
    gemm_nt_kernel<0><<<dim3(13, 5, 8), 256, 0, stream>>>(geneexpr, GENE_K, gene_w, GENE_K,
                                                          BB, GENE_N, GENE_K, 2475,
                                                          gpart, nullptr, nullptr);
    // 5. reduce + bias
    gene_reduce_kernel<<<1000, 256, 0, stream>>>(gpart, gene_b, gene);
    // 6. BN stats
    bn_stats_kernel<<<GENE_N, 256, 0, stream>>>(gene, stats);
    // 7. BN apply + relu (in place)
    bn_apply_kernel<<<1000, 256, 0, stream>>>(gene, stats, bn_gamma, bn_beta);
    // 8. attention scores
    attn_kernel<<<LSTM_M, 64, 0, stream>>>(h, gene, attn);
    // 9. weighted/flat [800][14400]
    weighted_kernel<<<45000, 256, 0, stream>>>(h, attn, weighted);
    // 10. lin GEMM (split-K 4) -> partials
    gemm_nt_kernel<0><<<dim3(13, 15, 4), 256, 0, stream>>>(weighted, LIN_K, lin_w, LIN_K,
                                                           BB, LIN_N, LIN_K, 3600,
                                                           lpart, nullptr, nullptr);
    // 11. reduce + bias + relu -> hid
    lin_reduce_kernel<<<2891, 256, 0, stream>>>(lpart, lin_b, hid);
    // 12. final dot -> out[800]
    out_kernel<<<BB, 64, 0, stream>>>(hid, out_w, out_b, out);
}

// Round 3
// 1713.977 us; speedup vs baseline: 2.1705x; 2.1705x over previous
//
#include <hip/hip_runtime.h>
#include <hip/hip_bf16.h>
#include <math.h>

// Problem constants
#define BB   800
#define CIN  4
#define LIN  600
#define COUT 320
#define KW   26
#define TT   45
#define POOLW 13
#define HID  160
#define LSTM_N 1280          // 2 dirs * [jg(10) x gate(4) x jl(16)] permuted layout
#define LSTM_K 320
#define LSTM_M 36000         // T*B
#define GENE_K 19795
#define GENE_N 320
#define LIN_K 14400
#define LIN_N 925

// Workspace layout (float units)
#define OFF_SEQ    ((size_t)0)          // [45][800][320] f32 ; reused as weighted [800][14400]
#define OFF_H      ((size_t)11520000)   // [45][800][320] f32
#define OFF_BP     ((size_t)23040000)   // [1280][960] ushort (bf16 tripled) = 614400 f32-equiv
#define OFF_BIAS   ((size_t)23654400)   // [1280] f32
#define OFF_GPART  ((size_t)23655680)   // [8][800][320] f32
#define OFF_GENE   ((size_t)25703680)   // [800][320] f32
#define OFF_STATS  ((size_t)25959680)   // [640]
#define OFF_ATTN   ((size_t)25960320)   // [45*800]
#define OFF_LPART  ((size_t)25996320)   // [4][800][925]
#define OFF_HID    ((size_t)28956320)   // [800][925]

typedef __attribute__((ext_vector_type(8))) short short8v;
typedef __attribute__((ext_vector_type(8))) unsigned short ushort8v;
typedef __attribute__((ext_vector_type(4))) float f32x4;

__device__ __forceinline__ float sigf(float x) { return 1.0f / (1.0f + expf(-x)); }

// Truncation-based hi/lo split: f = hi + lo + O(2^-16 |f|)
__device__ __forceinline__ void split3(float f, unsigned& hi, unsigned& lo) {
    unsigned u = __float_as_uint(f);
    unsigned hu = u & 0xffff0000u;
    float d = f - __uint_as_float(hu);
    hi = u >> 16;
    lo = __float_as_uint(d) >> 16;
}

// ---------------------------------------------------------------------------
// LSTM weights: permuted n = dir*640 + jg*64 + gate*16 + jl (j = jg*16+jl),
// tripled bf16 pattern (hi,hi,lo). Fused bias.
// ---------------------------------------------------------------------------
__global__ void prep_lstm_kernel(const float* __restrict__ wf, const float* __restrict__ bif,
                                 const float* __restrict__ bhf,
                                 const float* __restrict__ wb, const float* __restrict__ bib,
                                 const float* __restrict__ bhb,
                                 unsigned short* __restrict__ Bp, float* __restrict__ biasv) {
    int idx = blockIdx.x * 256 + threadIdx.x;
    if (idx < LSTM_N * LSTM_K) {
        int n = idx / LSTM_K, k = idx % LSTM_K;
        int dir = n / 640, r = n % 640;
        int jg = r >> 6, rr = r & 63, gate = rr >> 4, jl = rr & 15;
        int srow = gate * HID + jg * 16 + jl;
        const float* w = dir ? wb : wf;
        float f = w[(size_t)srow * LSTM_K + k];
        unsigned hi, lo;
        split3(f, hi, lo);
        unsigned short* d = Bp + (size_t)n * 960 + 3 * k;
        d[0] = (unsigned short)hi;
        d[1] = (unsigned short)hi;
        d[2] = (unsigned short)lo;
    }
    if (idx < LSTM_N) {
        int n = idx;
        int dir = n / 640, r = n % 640;
        int jg = r >> 6, rr = r & 63, gate = rr >> 4, jl = rr & 15;
        int srow = gate * HID + jg * 16 + jl;
        biasv[n] = dir ? (bib[srow] + bhb[srow]) : (bif[srow] + bhf[srow]);
    }
}

// ---------------------------------------------------------------------------
// Fused Conv1d + ReLU + left-pad(14) + MaxPool(13) -> seq[t][b][c]
// ---------------------------------------------------------------------------
__global__ __launch_bounds__(512) void conv_pool_kernel(const float* __restrict__ x,
                                                        const float* __restrict__ cw,
                                                        const float* __restrict__ cb,
                                                        float* __restrict__ seq) {
    __shared__ float wlds[COUT * CIN * KW];
    __shared__ float xs[CIN][312];
    int b = blockIdx.x;
    int tid = threadIdx.x;
    for (int i = tid; i < COUT * CIN * KW; i += 512) wlds[i] = cw[i];

    for (int ph = 0; ph < 2; ++ph) {
        int t0 = ph ? 23 : 0;
        int t1 = ph ? 45 : 23;
        int xstart = ph ? 285 : 0;
        int xlen = ph ? 311 : 310;
        __syncthreads();
        for (int i = tid; i < CIN * xlen; i += 512) {
            int ch = i / xlen, l = i % xlen;
            xs[ch][l] = x[((size_t)b * CIN + ch) * LIN + xstart + l];
        }
        __syncthreads();
        int nt = t1 - t0;
        int npairs = COUT * nt;
        for (int idx = tid; idx < npairs; idx += 512) {
            int c = idx / nt;
            int t = t0 + idx % nt;
            int base = t * POOLW - 14;
            int xbase = base - xstart;
            float bias_c = cb[c];
            float accv[13];
#pragma unroll
            for (int j = 0; j < 13; ++j) accv[j] = bias_c;
#pragma unroll
            for (int ch = 0; ch < CIN; ++ch) {
                float xw[38];
#pragma unroll
                for (int ii = 0; ii < 38; ++ii) {
                    int xi = xbase + ii;
                    xw[ii] = (xi >= 0 && xi < xlen) ? xs[ch][xi] : 0.0f;
                }
#pragma unroll
                for (int k = 0; k < KW; ++k) {
                    float wv = wlds[c * (CIN * KW) + ch * KW + k];
#pragma unroll
                    for (int j = 0; j < 13; ++j) accv[j] = fmaf(xw[j + k], wv, accv[j]);
                }
            }
            float mx = 0.0f;
#pragma unroll
            for (int j = 0; j < 13; ++j) {
                if (base + j >= 0) mx = fmaxf(mx, accv[j]);
            }
            seq[((size_t)t * BB + b) * COUT + c] = mx;
        }
    }
}

// ---------------------------------------------------------------------------
// Split-bf16 MFMA GEMM: out[r][n] = sum_k A[r][k]*B[n][k] in ~fp32 precision.
// Tile 128x128, 4 waves (each 64x64 = 4x4 frags of 16x16), K-chunk 32 orig-k
// = 96 tripled-k = 3 MFMA k-steps. A pattern (hi,lo,hi); B pattern (hi,hi,lo).
// MODE 0: split-K partials [sp][M][N]. MODE 1: LSTM activation epilogue.
// BPRE: B comes pre-tripled bf16 from global (LSTM weights).
// ---------------------------------------------------------------------------
__device__ __forceinline__ void load_f32_tile(const float* __restrict__ P, int ld, int r0, int R,
                                              int K, int k0, bool fast, int tid, float4* L) {
#pragma unroll
    for (int i = 0; i < 4; ++i) {
        int v = tid + i * 256;
        int r = v >> 3, kq = v & 7;
        int gr = r0 + r;
        float4 val = make_float4(0.f, 0.f, 0.f, 0.f);
        if (gr < R) {
            const float* p = P + (size_t)gr * ld + k0 + kq * 4;
            if (fast) {
                val = *reinterpret_cast<const float4*>(p);
            } else {
                int kb = k0 + kq * 4;
                if (kb + 0 < K) val.x = p[0];
                if (kb + 1 < K) val.y = p[1];
                if (kb + 2 < K) val.z = p[2];
                if (kb + 3 < K) val.w = p[3];
            }
        }
        L[i] = val;
    }
}

template <bool APAT>
__device__ __forceinline__ void write_trip_row(unsigned short* rowp, int kq, float4 val) {
    unsigned h[4], l[4];
    split3(val.x, h[0], l[0]);
    split3(val.y, h[1], l[1]);
    split3(val.z, h[2], l[2]);
    split3(val.w, h[3], l[3]);
    unsigned short t[12];
#pragma unroll
    for (int e = 0; e < 4; ++e) {
        t[3 * e + 0] = (unsigned short)h[e];
        t[3 * e + 1] = APAT ? (unsigned short)l[e] : (unsigned short)h[e];
        t[3 * e + 2] = APAT ? (unsigned short)h[e] : (unsigned short)l[e];
    }
    unsigned* d = reinterpret_cast<unsigned*>(rowp + 12 * kq);
#pragma unroll
    for (int q = 0; q < 6; ++q) d[q] = (unsigned)t[2 * q] | ((unsigned)t[2 * q + 1] << 16);
}

template <int MODE, bool BPRE>
__global__ __launch_bounds__(256) void mfma_gemm(const float* __restrict__ A, int lda,
                                                 const float* __restrict__ Bf, int ldb,
                                                 const unsigned short* __restrict__ Bp, int ldbp,
                                                 int M, int N, int K, int chunksPerSplit,
                                                 float* __restrict__ outp,
                                                 const float* __restrict__ biasv,
                                                 float* __restrict__ hout) {
    __shared__ unsigned short As[128][104];
    __shared__ unsigned short Bs[128][104];
    const int tid = threadIdx.x;
    const int bm = blockIdx.x, bn = blockIdx.y, sp = blockIdx.z;
    const int row0 = bm * 128, col0 = bn * 128;
    const int totChunks = (K + 31) >> 5;
    const int c_beg = sp * chunksPerSplit;
    const int c_end = min(totChunks, c_beg + chunksPerSplit);

    const int w = tid >> 6, lane = tid & 63;
    const int wr = w >> 1, wc = w & 1;
    const int l15 = lane & 15, lq = lane >> 4;

    f32x4 acc[4][4];
#pragma unroll
    for (int m = 0; m < 4; ++m)
#pragma unroll
        for (int n = 0; n < 4; ++n) acc[m][n] = (f32x4){0.f, 0.f, 0.f, 0.f};

    float4 aL[4];
    float4 bL[4];
    ushort8v bP[6];

    // prefetch first chunk
    {
        int k0 = c_beg * 32;
        bool fastA = ((lda & 3) == 0) && (k0 + 32 <= K);
        load_f32_tile(A, lda, row0, M, K, k0, fastA, tid, aL);
        if (!BPRE) {
            bool fastB = ((ldb & 3) == 0) && (k0 + 32 <= K);
            load_f32_tile(Bf, ldb, col0, N, K, k0, fastB, tid, bL);
        } else {
#pragma unroll
            for (int i = 0; i < 6; ++i) {
                int v = tid + i * 256;
                int r = v / 12, seg = v - r * 12;
                int gc = col0 + r;
                ushort8v z = {0, 0, 0, 0, 0, 0, 0, 0};
                bP[i] = (gc < N) ? *reinterpret_cast<const ushort8v*>(
                                       Bp + (size_t)gc * ldbp + (size_t)c_beg * 96 + seg * 8)
                                 : z;
            }
        }
    }

    for (int c = c_beg; c < c_end; ++c) {
        __syncthreads();   // previous MFMA reads done; LDS free
        // write staged regs -> LDS (tripled bf16)
#pragma unroll
        for (int i = 0; i < 4; ++i) {
            int v = tid + i * 256;
            int r = v >> 3, kq = v & 7;
            write_trip_row<true>(&As[r][0], kq, aL[i]);
        }
        if (!BPRE) {
#pragma unroll
            for (int i = 0; i < 4; ++i) {
                int v = tid + i * 256;
                int r = v >> 3, kq = v & 7;
                write_trip_row<false>(&Bs[r][0], kq, bL[i]);
            }
        } else {
#pragma unroll
            for (int i = 0; i < 6; ++i) {
                int v = tid + i * 256;
                int r = v / 12, seg = v - r * 12;
                *reinterpret_cast<ushort8v*>(&Bs[r][seg * 8]) = bP[i];
            }
        }
        __syncthreads();

        // prefetch next chunk (overlaps MFMA below)
        if (c + 1 < c_end) {
            int k0 = (c + 1) * 32;
            bool fastA = ((lda & 3) == 0) && (k0 + 32 <= K);
            load_f32_tile(A, lda, row0, M, K, k0, fastA, tid, aL);
            if (!BPRE) {
                bool fastB = ((ldb & 3) == 0) && (k0 + 32 <= K);
                load_f32_tile(Bf, ldb, col0, N, K, k0, fastB, tid, bL);
            } else {
#pragma unroll
                for (int i = 0; i < 6; ++i) {
                    int v = tid + i * 256;
                    int r = v / 12, seg = v - r * 12;
                    int gc = col0 + r;
                    ushort8v z = {0, 0, 0, 0, 0, 0, 0, 0};
                    bP[i] = (gc < N) ? *reinterpret_cast<const ushort8v*>(
                                           Bp + (size_t)gc * ldbp + (size_t)(c + 1) * 96 + seg * 8)
                                     : z;
                }
            }
        }

        // MFMA: 3 k-steps x 16 fragments
#pragma unroll
        for (int ks = 0; ks < 3; ++ks) {
            short8v af[4], bf4[4];
#pragma unroll
            for (int m = 0; m < 4; ++m)
                af[m] = *reinterpret_cast<const short8v*>(&As[wr * 64 + m * 16 + l15][ks * 32 + lq * 8]);
#pragma unroll
            for (int n = 0; n < 4; ++n)
                bf4[n] = *reinterpret_cast<const short8v*>(&Bs[wc * 64 + n * 16 + l15][ks * 32 + lq * 8]);
#pragma unroll
            for (int m = 0; m < 4; ++m)
#pragma unroll
                for (int n = 0; n < 4; ++n)
                    acc[m][n] = __builtin_amdgcn_mfma_f32_16x16x32_bf16(af[m], bf4[n], acc[m][n], 0, 0, 0);
        }
    }

    if (MODE == 0) {
#pragma unroll
        for (int m = 0; m < 4; ++m)
#pragma unroll
            for (int n = 0; n < 4; ++n)
#pragma unroll
                for (int rg = 0; rg < 4; ++rg) {
                    int row_g = row0 + wr * 64 + m * 16 + lq * 4 + rg;
                    int col_g = col0 + wc * 64 + n * 16 + l15;
                    if (row_g < M && col_g < N)
                        outp[((size_t)sp * M + row_g) * N + col_g] = acc[m][n][rg];
                }
    } else {
        // LSTM epilogue: fragment-col index == gate (i,f,g,o)
        int c0 = col0 + wc * 64;
        int dir = c0 / 640;
        int jgl = (c0 % 640) >> 6;
        int hcol = dir * HID + jgl * 16 + l15;
        float bi = biasv[c0 + l15];
        float bg = biasv[c0 + 32 + l15];
        float bo = biasv[c0 + 48 + l15];
#pragma unroll
        for (int m = 0; m < 4; ++m)
#pragma unroll
            for (int rg = 0; rg < 4; ++rg) {
                int row_g = row0 + wr * 64 + m * 16 + lq * 4 + rg;
                if (row_g >= M) continue;
                float gi = acc[m][0][rg] + bi;
                float gg = acc[m][2][rg] + bg;
                float go = acc[m][3][rg] + bo;
                float cc = sigf(gi) * tanhf(gg);
                hout[(size_t)row_g * 320 + hcol] = sigf(go) * tanhf(cc);
            }
    }
}

// ---------------------------------------------------------------------------
__global__ void gene_reduce_kernel(const float* __restrict__ part, const float* __restrict__ gene_b,
                                   float* __restrict__ out) {
    int idx = blockIdx.x * 256 + threadIdx.x;
    if (idx >= BB * GENE_N) return;
    int n = idx % GENE_N;
    float sum = gene_b[n];
#pragma unroll
    for (int ss = 0; ss < 8; ++ss) sum += part[(size_t)ss * (BB * GENE_N) + idx];
    out[idx] = sum;
}

__global__ void bn_stats_kernel(const float* __restrict__ g, float* __restrict__ stats) {
    int n = blockIdx.x;
    int tid = threadIdx.x;
    float s = 0.0f, s2 = 0.0f;
    for (int m = tid; m < BB; m += 256) {
        float v = g[(size_t)m * GENE_N + n];
        s += v;
        s2 += v * v;
    }
    __shared__ float red0[256], red1[256];
    red0[tid] = s; red1[tid] = s2;
    __syncthreads();
    for (int off = 128; off; off >>= 1) {
        if (tid < off) { red0[tid] += red0[tid + off]; red1[tid] += red1[tid + off]; }
        __syncthreads();
    }
    if (tid == 0) {
        float mean = red0[0] / (float)BB;
        float var = red1[0] / (float)BB - mean * mean;
        stats[n] = mean;
        stats[GENE_N + n] = rsqrtf(var + 1e-5f);
    }
}

__global__ void bn_apply_kernel(float* __restrict__ g, const float* __restrict__ stats,
                                const float* __restrict__ gamma, const float* __restrict__ beta) {
    int idx = blockIdx.x * 256 + threadIdx.x;
    if (idx >= BB * GENE_N) return;
    int n = idx % GENE_N;
    float v = (g[idx] - stats[n]) * stats[GENE_N + n] * gamma[n] + beta[n];
    g[idx] = fmaxf(v, 0.0f);
}

__global__ void attn_kernel(const float* __restrict__ h, const float* __restrict__ gene,
                            float* __restrict__ attn) {
    int r = blockIdx.x;
    int b = r % BB;
    int lane = threadIdx.x;
    const float* hr = h + (size_t)r * 320;
    const float* gr = gene + (size_t)b * 320;
    float s = 0.0f;
    for (int d = lane; d < 320; d += 64) s += hr[d] * gr[d];
    for (int off = 32; off; off >>= 1) s += __shfl_down(s, off);
    if (lane == 0) attn[r] = s;
}

__global__ void weighted_kernel(const float* __restrict__ h, const float* __restrict__ attn,
                                float* __restrict__ wout) {
    int idx = blockIdx.x * 256 + threadIdx.x;
    if (idx >= BB * TT * 320) return;
    int b = idx / (TT * 320);
    int rem = idx % (TT * 320);
    int t = rem / 320;
    int d = rem % 320;
    int r = t * BB + b;
    wout[idx] = attn[r] * h[(size_t)r * 320 + d];
}

__global__ void lin_reduce_kernel(const float* __restrict__ part, const float* __restrict__ lin_b,
                                  float* __restrict__ hid) {
    int idx = blockIdx.x * 256 + threadIdx.x;
    if (idx >= BB * LIN_N) return;
    int n = idx % LIN_N;
    float sum = lin_b[n];
#pragma unroll
    for (int ss = 0; ss < 4; ++ss) sum += part[(size_t)ss * (BB * LIN_N) + idx];
    hid[idx] = fmaxf(sum, 0.0f);
}

__global__ void out_kernel(const float* __restrict__ hid, const float* __restrict__ ow,
                           const float* __restrict__ ob, float* __restrict__ out) {
    int b = blockIdx.x;
    int lane = threadIdx.x;
    float s = 0.0f;
    for (int n = lane; n < LIN_N; n += 64) s += hid[(size_t)b * LIN_N + n] * ow[n];
    for (int off = 32; off; off >>= 1) s += __shfl_down(s, off);
    if (lane == 0) out[b] = s + ob[0];
}

// ---------------------------------------------------------------------------
extern "C" void kernel_launch(void* const* d_in, const int* in_sizes, int n_in,
                              void* d_out, int out_size, void* d_ws, size_t ws_size,
                              hipStream_t stream) {
    const float* x        = (const float*)d_in[0];
    const float* geneexpr = (const float*)d_in[1];
    const float* conv_w   = (const float*)d_in[2];
    const float* conv_b   = (const float*)d_in[3];
    const float* w_ih_f   = (const float*)d_in[4];
    const float* b_ih_f   = (const float*)d_in[5];
    const float* b_hh_f   = (const float*)d_in[6];
    const float* w_ih_b   = (const float*)d_in[7];
    const float* b_ih_b   = (const float*)d_in[8];
    const float* b_hh_b   = (const float*)d_in[9];
    const float* gene_w   = (const float*)d_in[10];
    const float* gene_b   = (const float*)d_in[11];
    const float* bn_gamma = (const float*)d_in[12];
    const float* bn_beta  = (const float*)d_in[13];
    const float* lin_w    = (const float*)d_in[14];
    const float* lin_b    = (const float*)d_in[15];
    const float* out_w    = (const float*)d_in[16];
    const float* out_b    = (const float*)d_in[17];

    float* ws  = (float*)d_ws;
    float* out = (float*)d_out;

    float* seq            = ws + OFF_SEQ;
    float* h              = ws + OFF_H;
    unsigned short* Bp    = (unsigned short*)(ws + OFF_BP);
    float* biasv          = ws + OFF_BIAS;
    float* gpart          = ws + OFF_GPART;
    float* gene           = ws + OFF_GENE;
    float* stats          = ws + OFF_STATS;
    float* attn           = ws + OFF_ATTN;
    float* weighted       = ws + OFF_SEQ;     // reuse seq after LSTM
    float* lpart          = ws + OFF_LPART;
    float* hid            = ws + OFF_HID;

    // 1. LSTM weights: permute + triple to bf16, fuse bias
    prep_lstm_kernel<<<1600, 256, 0, stream>>>(w_ih_f, b_ih_f, b_hh_f,
                                               w_ih_b, b_ih_b, b_hh_b, Bp, biasv);
    // 2. conv + relu + pad + maxpool -> seq[t][b][c]
    conv_pool_kernel<<<BB, 512, 0, stream>>>(x, conv_w, conv_b, seq);
    // 3. LSTM gates MFMA GEMM + activation epilogue -> h
    mfma_gemm<1, true><<<dim3(282, 10, 1), 256, 0, stream>>>(
        seq, LSTM_K, nullptr, 0, Bp, 960, LSTM_M, LSTM_N, LSTM_K, 10,
        nullptr, biasv, h);
    // 4. gene MFMA GEMM (split-K 8): 619 chunks -> 78/split
    mfma_gemm<0, false><<<dim3(7, 3, 8), 256, 0, stream>>>(
        geneexpr, GENE_K, gene_w, GENE_K, nullptr, 0, BB, GENE_N, GENE_K, 78,
        gpart, nullptr, nullptr);
    // 5. reduce + bias
    gene_reduce_kernel<<<1000, 256, 0, stream>>>(gpart, gene_b, gene);
    // 6-7. BN
    bn_stats_kernel<<<GENE_N, 256, 0, stream>>>(gene, stats);
    bn_apply_kernel<<<1000, 256, 0, stream>>>(gene, stats, bn_gamma, bn_beta);
    // 8. attention scores
    attn_kernel<<<LSTM_M, 64, 0, stream>>>(h, gene, attn);
    // 9. weighted/flat [800][14400]
    weighted_kernel<<<45000, 256, 0, stream>>>(h, attn, weighted);
    // 10. lin MFMA GEMM (split-K 4): 450 chunks -> 113/split
    mfma_gemm<0, false><<<dim3(7, 8, 4), 256, 0, stream>>>(
        weighted, LIN_K, lin_w, LIN_K, nullptr, 0, BB, LIN_N, LIN_K, 113,
        lpart, nullptr, nullptr);
    // 11. reduce + bias + relu
    lin_reduce_kernel<<<2891, 256, 0, stream>>>(lpart, lin_b, hid);
    // 12. final dot
    out_kernel<<<BB, 64, 0, stream>>>(hid, out_w, out_b, out);
}

// Round 4
// 1227.864 us; speedup vs baseline: 3.0299x; 1.3959x over previous
//
#include <hip/hip_runtime.h>
#include <hip/hip_bf16.h>
#include <math.h>

// Problem constants
#define BB   800
#define CIN  4
#define XLEN 600
#define COUT 320
#define KW   26
#define TT   45
#define POOLW 13
#define HID  160
#define LSTM_N 1280          // 2 dirs * [jg(10) x gate(4) x jl(16)] permuted layout
#define LSTM_K 320
#define LSTM_M 36000         // T*B
#define GENE_K 19795
#define GENE_N 320
#define LIN_K 14400
#define LIN_N 925
#define GENE_SPLITS 31
#define LIN_SPLITS 8

// Workspace layout (float units)
#define OFF_SEQ    ((size_t)0)          // [45][800][320] f32; later aliased by gpart/lpart
#define OFF_H      ((size_t)11520000)   // [45][800][320] f32
#define OFF_BP     ((size_t)23040000)   // [1280][960] ushort (bf16 tripled)
#define OFF_BIAS   ((size_t)23654400)   // [1280] f32
#define OFF_WD     ((size_t)23655680)   // [320][224] ushort (conv w doubled)
#define OFF_GENE   ((size_t)23691520)   // [800][320] f32
#define OFF_STATS  ((size_t)23947520)   // [640]
#define OFF_ATTN   ((size_t)23948160)   // [45*800]
#define OFF_HID    ((size_t)23984160)   // [800][925]

typedef __attribute__((ext_vector_type(8))) short short8v;
typedef __attribute__((ext_vector_type(8))) unsigned short ushort8v;
typedef __attribute__((ext_vector_type(4))) float f32x4;

__device__ __forceinline__ float sigf(float x) { return 1.0f / (1.0f + expf(-x)); }

// Truncation-based hi/lo split: f = hi + lo + O(2^-16 |f|)
__device__ __forceinline__ void split3(float f, unsigned& hi, unsigned& lo) {
    unsigned u = __float_as_uint(f);
    unsigned hu = u & 0xffff0000u;
    float d = f - __uint_as_float(hu);
    hi = u >> 16;
    lo = __float_as_uint(d) >> 16;
}

// ---------------------------------------------------------------------------
// LSTM weights: permuted n = dir*640 + jg*64 + gate*16 + jl, tripled (hi,hi,lo)
// ---------------------------------------------------------------------------
__global__ void prep_lstm_kernel(const float* __restrict__ wf, const float* __restrict__ bif,
                                 const float* __restrict__ bhf,
                                 const float* __restrict__ wb, const float* __restrict__ bib,
                                 const float* __restrict__ bhb,
                                 unsigned short* __restrict__ Bp, float* __restrict__ biasv) {
    int idx = blockIdx.x * 256 + threadIdx.x;
    if (idx < LSTM_N * LSTM_K) {
        int n = idx / LSTM_K, k = idx % LSTM_K;
        int dir = n / 640, r = n % 640;
        int jg = r >> 6, rr = r & 63, gate = rr >> 4, jl = rr & 15;
        int srow = gate * HID + jg * 16 + jl;
        const float* w = dir ? wb : wf;
        float f = w[(size_t)srow * LSTM_K + k];
        unsigned hi, lo;
        split3(f, hi, lo);
        unsigned short* d = Bp + (size_t)n * 960 + 3 * k;
        d[0] = (unsigned short)hi;
        d[1] = (unsigned short)hi;
        d[2] = (unsigned short)lo;
    }
    if (idx < LSTM_N) {
        int n = idx;
        int dir = n / 640, r = n % 640;
        int jg = r >> 6, rr = r & 63, gate = rr >> 4, jl = rr & 15;
        int srow = gate * HID + jg * 16 + jl;
        biasv[n] = dir ? (bib[srow] + bhb[srow]) : (bif[srow] + bhf[srow]);
    }
}

// ---------------------------------------------------------------------------
// Conv weights doubled bf16 (RNE hi, duplicated): wd[c][2k+0]=wd[c][2k+1]=hi.
// Cols 208..223 zero.
// ---------------------------------------------------------------------------
__global__ void prep_convw_kernel(const float* __restrict__ cw, unsigned short* __restrict__ wd) {
    int idx = blockIdx.x * 256 + threadIdx.x;
    if (idx < COUT * 104) {
        int c = idx / 104, k = idx % 104;
        float f = cw[(size_t)c * 104 + k];
        unsigned u = __float_as_uint(f);
        unsigned rn = (u + 0x7fffu + ((u >> 16) & 1u)) >> 16;   // RNE bf16
        unsigned short* d = wd + (size_t)c * 224 + 2 * k;
        d[0] = (unsigned short)rn;
        d[1] = (unsigned short)rn;
    }
    if (idx < COUT * 16) {
        int c = idx / 16, k = idx % 16;
        wd[(size_t)c * 224 + 208 + k] = 0;
    }
}

// ---------------------------------------------------------------------------
// Fused Conv1d(4->320,k=26) + bias + ReLU + left-pad(14) + MaxPool(13) via MFMA.
// Block: (b, wtile of 9 pool windows = 117 positions, 128-col ctile).
// Rows r=0..127 <-> conv position p0+r, p0 = 117*wtile-14. K doubled = 208
// (A: x_hi,x_lo ; B: w_hi,w_hi), 7 MFMA k-steps. Pool+bias+ReLU epilogue via
// LDS C-scratch. seq[t][b][c] written directly.
// ---------------------------------------------------------------------------
#define CSTR 232   // LDS row stride (ushorts): 464B ≡ 20 banks mod 32 -> ~2-way

__global__ __launch_bounds__(256) void conv_mfma_kernel(const float* __restrict__ x,
                                                        const unsigned short* __restrict__ wd,
                                                        const float* __restrict__ cb,
                                                        float* __restrict__ seq) {
    __shared__ unsigned short lds[2][128][CSTR];   // As / Bs ; 118784 B
    int bx = blockIdx.x;
    int b = bx / 5, wt = bx % 5;
    int col0 = blockIdx.y * 128;
    int p0 = 117 * wt - 14;
    int tid = threadIdx.x;

    // stage A: x tripled... doubled (hi,lo) per k
    const float* xb = x + (size_t)b * (CIN * XLEN);
#pragma unroll
    for (int i = 0; i < 14; ++i) {
        int j = i * 256 + tid;          // < 3584 = 128 * 28
        int r = j & 127, kg = j >> 7;   // kg in [0,28)
        ushort8v o = {0, 0, 0, 0, 0, 0, 0, 0};
        if (kg < 26) {
#pragma unroll
            for (int e = 0; e < 4; ++e) {
                int k = kg * 4 + e;
                int ch = k / 26, kk = k - ch * 26;
                int p = p0 + r + kk;
                float v = (p >= 0 && p < XLEN) ? xb[ch * XLEN + p] : 0.0f;
                unsigned hi, lo;
                split3(v, hi, lo);
                o[2 * e] = (unsigned short)hi;
                o[2 * e + 1] = (unsigned short)lo;
            }
        }
        *reinterpret_cast<ushort8v*>(&lds[0][r][kg * 8]) = o;
    }
    // stage B: pre-doubled weights
#pragma unroll
    for (int i = 0; i < 14; ++i) {
        int j = i * 256 + tid;          // < 3584 = 128 * 28
        int c = j / 28, seg = j - c * 28;
        int cg = col0 + c;
        ushort8v o = {0, 0, 0, 0, 0, 0, 0, 0};
        if (cg < COUT) o = *reinterpret_cast<const ushort8v*>(wd + (size_t)cg * 224 + seg * 8);
        *reinterpret_cast<ushort8v*>(&lds[1][c][seg * 8]) = o;
    }
    __syncthreads();

    const int w = tid >> 6, lane = tid & 63;
    const int wr = w >> 1, wc = w & 1;
    const int l15 = lane & 15, lq = lane >> 4;

    f32x4 acc[4][4];
#pragma unroll
    for (int m = 0; m < 4; ++m)
#pragma unroll
        for (int n = 0; n < 4; ++n) acc[m][n] = (f32x4){0.f, 0.f, 0.f, 0.f};

#pragma unroll
    for (int ks = 0; ks < 7; ++ks) {
        short8v af[4], bf[4];
#pragma unroll
        for (int m = 0; m < 4; ++m)
            af[m] = *reinterpret_cast<const short8v*>(&lds[0][wr * 64 + m * 16 + l15][ks * 32 + lq * 8]);
#pragma unroll
        for (int n = 0; n < 4; ++n)
            bf[n] = *reinterpret_cast<const short8v*>(&lds[1][wc * 64 + n * 16 + l15][ks * 32 + lq * 8]);
#pragma unroll
        for (int m = 0; m < 4; ++m)
#pragma unroll
            for (int n = 0; n < 4; ++n)
                acc[m][n] = __builtin_amdgcn_mfma_f32_16x16x32_bf16(af[m], bf[n], acc[m][n], 0, 0, 0);
    }
    __syncthreads();

    // acc -> LDS C scratch [128][128] f32
    float* Cs = reinterpret_cast<float*>(&lds[0][0][0]);
#pragma unroll
    for (int m = 0; m < 4; ++m)
#pragma unroll
        for (int n = 0; n < 4; ++n)
#pragma unroll
            for (int rg = 0; rg < 4; ++rg) {
                int row = wr * 64 + m * 16 + lq * 4 + rg;
                int col = wc * 64 + n * 16 + l15;
                Cs[row * 128 + col] = acc[m][n][rg];
            }
    __syncthreads();

    // pool 9 windows x 128 cols
#pragma unroll
    for (int i = 0; i < 5; ++i) {
        int j = i * 256 + tid;
        if (j < 9 * 128) {
            int u = j >> 7, c = j & 127;
            int cg = col0 + c;
            if (cg < COUT) {
                float bias = cb[cg];
                float mx = 0.0f;
#pragma unroll
                for (int jj = 0; jj < 13; ++jj) {
                    int r = 13 * u + jj;
                    int p = p0 + r;
                    if (p >= 0 && p < 575) mx = fmaxf(mx, Cs[r * 128 + c] + bias);
                }
                int t = wt * 9 + u;
                seq[((size_t)t * BB + b) * COUT + cg] = mx;
            }
        }
    }
}

// ---------------------------------------------------------------------------
// Split-bf16 MFMA GEMM (tile 128x128, 4 waves, K-chunk 32 -> tripled 96).
// MODE 0: split-K partials. MODE 1: LSTM activation epilogue.
// BPRE: B pre-tripled in global. AFUSE: A[r][k] = attn[t*800+r]*h[(t*800+r)][d].
// ---------------------------------------------------------------------------
__device__ __forceinline__ void load_f32_tile(const float* __restrict__ P, int ld, int r0, int R,
                                              int K, int k0, bool fast, int tid, float4* L) {
#pragma unroll
    for (int i = 0; i < 4; ++i) {
        int v = tid + i * 256;
        int r = v >> 3, kq = v & 7;
        int gr = r0 + r;
        float4 val = make_float4(0.f, 0.f, 0.f, 0.f);
        if (gr < R) {
            const float* p = P + (size_t)gr * ld + k0 + kq * 4;
            if (fast) {
                val = *reinterpret_cast<const float4*>(p);
            } else {
                int kb = k0 + kq * 4;
                if (kb + 0 < K) val.x = p[0];
                if (kb + 1 < K) val.y = p[1];
                if (kb + 2 < K) val.z = p[2];
                if (kb + 3 < K) val.w = p[3];
            }
        }
        L[i] = val;
    }
}

template <bool APAT>
__device__ __forceinline__ void write_trip_row(unsigned short* rowp, int kq, float4 val) {
    unsigned h[4], l[4];
    split3(val.x, h[0], l[0]);
    split3(val.y, h[1], l[1]);
    split3(val.z, h[2], l[2]);
    split3(val.w, h[3], l[3]);
    unsigned short t[12];
#pragma unroll
    for (int e = 0; e < 4; ++e) {
        t[3 * e + 0] = (unsigned short)h[e];
        t[3 * e + 1] = APAT ? (unsigned short)l[e] : (unsigned short)h[e];
        t[3 * e + 2] = APAT ? (unsigned short)h[e] : (unsigned short)l[e];
    }
    unsigned* d = reinterpret_cast<unsigned*>(rowp + 12 * kq);
#pragma unroll
    for (int q = 0; q < 6; ++q) d[q] = (unsigned)t[2 * q] | ((unsigned)t[2 * q + 1] << 16);
}

template <int MODE, bool BPRE, bool AFUSE>
__global__ __launch_bounds__(256) void mfma_gemm(const float* __restrict__ A, int lda,
                                                 const float* __restrict__ Bf, int ldb,
                                                 const unsigned short* __restrict__ Bp, int ldbp,
                                                 const float* __restrict__ attnp,
                                                 int M, int N, int K, int chunksPerSplit,
                                                 float* __restrict__ outp,
                                                 const float* __restrict__ biasv,
                                                 float* __restrict__ hout) {
    __shared__ unsigned short As[128][104];
    __shared__ unsigned short Bs[128][104];
    const int tid = threadIdx.x;
    const int bm = blockIdx.x, bn = blockIdx.y, sp = blockIdx.z;
    const int row0 = bm * 128, col0 = bn * 128;
    const int totChunks = (K + 31) >> 5;
    const int c_beg = sp * chunksPerSplit;
    const int c_end = min(totChunks, c_beg + chunksPerSplit);

    const int w = tid >> 6, lane = tid & 63;
    const int wr = w >> 1, wc = w & 1;
    const int l15 = lane & 15, lq = lane >> 4;

    f32x4 acc[4][4];
#pragma unroll
    for (int m = 0; m < 4; ++m)
#pragma unroll
        for (int n = 0; n < 4; ++n) acc[m][n] = (f32x4){0.f, 0.f, 0.f, 0.f};

    float4 aL[4];
    float4 bL[4];
    ushort8v bP[6];

    // ---- A-load helper (as lambda-free macro style) ----
    auto loadA = [&](int k0) {
        if (AFUSE) {
            int t = k0 / 320;
            int d0 = k0 - t * 320;
            const float* hb = A + (size_t)t * (BB * 320);
            const float* ab = attnp + t * BB;
#pragma unroll
            for (int i = 0; i < 4; ++i) {
                int v = tid + i * 256;
                int r = v >> 3, kq = v & 7;
                int gr = row0 + r;
                float4 val = make_float4(0.f, 0.f, 0.f, 0.f);
                if (gr < M) {
                    val = *reinterpret_cast<const float4*>(hb + (size_t)gr * 320 + d0 + kq * 4);
                    float aw = ab[gr];
                    val.x *= aw; val.y *= aw; val.z *= aw; val.w *= aw;
                }
                aL[i] = val;
            }
        } else {
            bool fastA = ((lda & 3) == 0) && (k0 + 32 <= K);
            load_f32_tile(A, lda, row0, M, K, k0, fastA, tid, aL);
        }
    };
    auto loadB = [&](int c) {
        if (!BPRE) {
            int k0 = c * 32;
            bool fastB = ((ldb & 3) == 0) && (k0 + 32 <= K);
            load_f32_tile(Bf, ldb, col0, N, K, k0, fastB, tid, bL);
        } else {
#pragma unroll
            for (int i = 0; i < 6; ++i) {
                int v = tid + i * 256;
                int r = v / 12, seg = v - r * 12;
                int gc = col0 + r;
                ushort8v z = {0, 0, 0, 0, 0, 0, 0, 0};
                bP[i] = (gc < N) ? *reinterpret_cast<const ushort8v*>(
                                       Bp + (size_t)gc * ldbp + (size_t)c * 96 + seg * 8)
                                 : z;
            }
        }
    };

    loadA(c_beg * 32);
    loadB(c_beg);

    for (int c = c_beg; c < c_end; ++c) {
        __syncthreads();
#pragma unroll
        for (int i = 0; i < 4; ++i) {
            int v = tid + i * 256;
            int r = v >> 3, kq = v & 7;
            write_trip_row<true>(&As[r][0], kq, aL[i]);
        }
        if (!BPRE) {
#pragma unroll
            for (int i = 0; i < 4; ++i) {
                int v = tid + i * 256;
                int r = v >> 3, kq = v & 7;
                write_trip_row<false>(&Bs[r][0], kq, bL[i]);
            }
        } else {
#pragma unroll
            for (int i = 0; i < 6; ++i) {
                int v = tid + i * 256;
                int r = v / 12, seg = v - r * 12;
                *reinterpret_cast<ushort8v*>(&Bs[r][seg * 8]) = bP[i];
            }
        }
        __syncthreads();

        if (c + 1 < c_end) {
            loadA((c + 1) * 32);
            loadB(c + 1);
        }

#pragma unroll
        for (int ks = 0; ks < 3; ++ks) {
            short8v af[4], bf4[4];
#pragma unroll
            for (int m = 0; m < 4; ++m)
                af[m] = *reinterpret_cast<const short8v*>(&As[wr * 64 + m * 16 + l15][ks * 32 + lq * 8]);
#pragma unroll
            for (int n = 0; n < 4; ++n)
                bf4[n] = *reinterpret_cast<const short8v*>(&Bs[wc * 64 + n * 16 + l15][ks * 32 + lq * 8]);
#pragma unroll
            for (int m = 0; m < 4; ++m)
#pragma unroll
                for (int n = 0; n < 4; ++n)
                    acc[m][n] = __builtin_amdgcn_mfma_f32_16x16x32_bf16(af[m], bf4[n], acc[m][n], 0, 0, 0);
        }
    }

    if (MODE == 0) {
#pragma unroll
        for (int m = 0; m < 4; ++m)
#pragma unroll
            for (int n = 0; n < 4; ++n)
#pragma unroll
                for (int rg = 0; rg < 4; ++rg) {
                    int row_g = row0 + wr * 64 + m * 16 + lq * 4 + rg;
                    int col_g = col0 + wc * 64 + n * 16 + l15;
                    if (row_g < M && col_g < N)
                        outp[((size_t)sp * M + row_g) * N + col_g] = acc[m][n][rg];
                }
    } else {
        int c0 = col0 + wc * 64;
        int dir = c0 / 640;
        int jgl = (c0 % 640) >> 6;
        int hcol = dir * HID + jgl * 16 + l15;
        float bi = biasv[c0 + l15];
        float bg = biasv[c0 + 32 + l15];
        float bo = biasv[c0 + 48 + l15];
#pragma unroll
        for (int m = 0; m < 4; ++m)
#pragma unroll
            for (int rg = 0; rg < 4; ++rg) {
                int row_g = row0 + wr * 64 + m * 16 + lq * 4 + rg;
                if (row_g >= M) continue;
                float gi = acc[m][0][rg] + bi;
                float gg = acc[m][2][rg] + bg;
                float go = acc[m][3][rg] + bo;
                float cc = sigf(gi) * tanhf(gg);
                hout[(size_t)row_g * 320 + hcol] = sigf(go) * tanhf(cc);
            }
    }
}

// ---------------------------------------------------------------------------
__global__ void gene_reduce_kernel(const float* __restrict__ part, const float* __restrict__ gene_b,
                                   float* __restrict__ out) {
    int idx = blockIdx.x * 256 + threadIdx.x;
    if (idx >= BB * GENE_N) return;
    int n = idx % GENE_N;
    float sum = gene_b[n];
#pragma unroll
    for (int ss = 0; ss < GENE_SPLITS; ++ss) sum += part[(size_t)ss * (BB * GENE_N) + idx];
    out[idx] = sum;
}

__global__ void bn_stats_kernel(const float* __restrict__ g, float* __restrict__ stats) {
    int n = blockIdx.x;
    int tid = threadIdx.x;
    float s = 0.0f, s2 = 0.0f;
    for (int m = tid; m < BB; m += 256) {
        float v = g[(size_t)m * GENE_N + n];
        s += v;
        s2 += v * v;
    }
    __shared__ float red0[256], red1[256];
    red0[tid] = s; red1[tid] = s2;
    __syncthreads();
    for (int off = 128; off; off >>= 1) {
        if (tid < off) { red0[tid] += red0[tid + off]; red1[tid] += red1[tid + off]; }
        __syncthreads();
    }
    if (tid == 0) {
        float mean = red0[0] / (float)BB;
        float var = red1[0] / (float)BB - mean * mean;
        stats[n] = mean;
        stats[GENE_N + n] = rsqrtf(var + 1e-5f);
    }
}

__global__ void bn_apply_kernel(float* __restrict__ g, const float* __restrict__ stats,
                                const float* __restrict__ gamma, const float* __restrict__ beta) {
    int idx = blockIdx.x * 256 + threadIdx.x;
    if (idx >= BB * GENE_N) return;
    int n = idx % GENE_N;
    float v = (g[idx] - stats[n]) * stats[GENE_N + n] * gamma[n] + beta[n];
    g[idx] = fmaxf(v, 0.0f);
}

__global__ void attn_kernel(const float* __restrict__ h, const float* __restrict__ gene,
                            float* __restrict__ attn) {
    int r = blockIdx.x;
    int b = r % BB;
    int lane = threadIdx.x;
    const float* hr = h + (size_t)r * 320;
    const float* gr = gene + (size_t)b * 320;
    float s = 0.0f;
    for (int d = lane; d < 320; d += 64) s += hr[d] * gr[d];
    for (int off = 32; off; off >>= 1) s += __shfl_down(s, off);
    if (lane == 0) attn[r] = s;
}

__global__ void lin_reduce_kernel(const float* __restrict__ part, const float* __restrict__ lin_b,
                                  float* __restrict__ hid) {
    int idx = blockIdx.x * 256 + threadIdx.x;
    if (idx >= BB * LIN_N) return;
    int n = idx % LIN_N;
    float sum = lin_b[n];
#pragma unroll
    for (int ss = 0; ss < LIN_SPLITS; ++ss) sum += part[(size_t)ss * (BB * LIN_N) + idx];
    hid[idx] = fmaxf(sum, 0.0f);
}

__global__ void out_kernel(const float* __restrict__ hid, const float* __restrict__ ow,
                           const float* __restrict__ ob, float* __restrict__ out) {
    int b = blockIdx.x;
    int lane = threadIdx.x;
    float s = 0.0f;
    for (int n = lane; n < LIN_N; n += 64) s += hid[(size_t)b * LIN_N + n] * ow[n];
    for (int off = 32; off; off >>= 1) s += __shfl_down(s, off);
    if (lane == 0) out[b] = s + ob[0];
}

// ---------------------------------------------------------------------------
extern "C" void kernel_launch(void* const* d_in, const int* in_sizes, int n_in,
                              void* d_out, int out_size, void* d_ws, size_t ws_size,
                              hipStream_t stream) {
    const float* x        = (const float*)d_in[0];
    const float* geneexpr = (const float*)d_in[1];
    const float* conv_w   = (const float*)d_in[2];
    const float* conv_b   = (const float*)d_in[3];
    const float* w_ih_f   = (const float*)d_in[4];
    const float* b_ih_f   = (const float*)d_in[5];
    const float* b_hh_f   = (const float*)d_in[6];
    const float* w_ih_b   = (const float*)d_in[7];
    const float* b_ih_b   = (const float*)d_in[8];
    const float* b_hh_b   = (const float*)d_in[9];
    const float* gene_w   = (const float*)d_in[10];
    const float* gene_b   = (const float*)d_in[11];
    const float* bn_gamma = (const float*)d_in[12];
    const float* bn_beta  = (const float*)d_in[13];
    const float* lin_w    = (const float*)d_in[14];
    const float* lin_b    = (const float*)d_in[15];
    const float* out_w    = (const float*)d_in[16];
    const float* out_b    = (const float*)d_in[17];

    float* ws  = (float*)d_ws;
    float* out = (float*)d_out;

    float* seq            = ws + OFF_SEQ;
    float* h              = ws + OFF_H;
    unsigned short* Bp    = (unsigned short*)(ws + OFF_BP);
    float* biasv          = ws + OFF_BIAS;
    unsigned short* wd    = (unsigned short*)(ws + OFF_WD);
    float* gene           = ws + OFF_GENE;
    float* stats          = ws + OFF_STATS;
    float* attn           = ws + OFF_ATTN;
    float* hid            = ws + OFF_HID;
    float* gpart          = ws + OFF_SEQ;   // alias (seq dead after LSTM GEMM)
    float* lpart          = ws + OFF_SEQ;   // alias (gpart dead after gene_reduce)

    // 1. LSTM weights triple + bias ; conv weights double
    prep_lstm_kernel<<<1600, 256, 0, stream>>>(w_ih_f, b_ih_f, b_hh_f,
                                               w_ih_b, b_ih_b, b_hh_b, Bp, biasv);
    prep_convw_kernel<<<130, 256, 0, stream>>>(conv_w, wd);
    // 2. fused conv+bias+relu+pad+pool via MFMA -> seq
    conv_mfma_kernel<<<dim3(BB * 5, 3, 1), 256, 0, stream>>>(x, wd, conv_b, seq);
    // 3. LSTM gates MFMA GEMM + activation epilogue -> h
    mfma_gemm<1, true, false><<<dim3(282, 10, 1), 256, 0, stream>>>(
        seq, LSTM_K, nullptr, 0, Bp, 960, nullptr, LSTM_M, LSTM_N, LSTM_K, 10,
        nullptr, biasv, h);
    // 4. gene MFMA GEMM (split-K 31, 20 chunks each)
    mfma_gemm<0, false, false><<<dim3(7, 3, GENE_SPLITS), 256, 0, stream>>>(
        geneexpr, GENE_K, gene_w, GENE_K, nullptr, 0, nullptr, BB, GENE_N, GENE_K, 20,
        gpart, nullptr, nullptr);
    // 5. reduce + bias
    gene_reduce_kernel<<<1000, 256, 0, stream>>>(gpart, gene_b, gene);
    // 6-7. BN
    bn_stats_kernel<<<GENE_N, 256, 0, stream>>>(gene, stats);
    bn_apply_kernel<<<1000, 256, 0, stream>>>(gene, stats, bn_gamma, bn_beta);
    // 8. attention scores
    attn_kernel<<<LSTM_M, 64, 0, stream>>>(h, gene, attn);
    // 9. lin MFMA GEMM (split-K 8, 57 chunks), A fused = attn*h on the fly
    mfma_gemm<0, false, true><<<dim3(7, 8, LIN_SPLITS), 256, 0, stream>>>(
        h, 320, lin_w, LIN_K, nullptr, 0, attn, BB, LIN_N, LIN_K, 57,
        lpart, nullptr, nullptr);
    // 10. reduce + bias + relu
    lin_reduce_kernel<<<2891, 256, 0, stream>>>(lpart, lin_b, hid);
    // 11. final dot
    out_kernel<<<BB, 64, 0, stream>>>(hid, out_w, out_b, out);
}

// Round 5
// 888.205 us; speedup vs baseline: 4.1885x; 1.3824x over previous
//
#include <hip/hip_runtime.h>
#include <hip/hip_bf16.h>
#include <math.h>

// Problem constants
#define BB   800
#define CIN  4
#define XLEN 600
#define COUT 320
#define KW   26
#define TT   45
#define POOLW 13
#define HID  160
#define LSTM_N 1280          // 2 dirs * [jg(10) x gate(4) x jl(16)] permuted layout
#define LSTM_K 320
#define LSTM_M 36000         // T*B
#define GENE_K 19795
#define GENE_N 320
#define LIN_K 14400
#define LIN_N 925
#define GENE_SPLITS 31
#define LIN_SPLITS 8

// Workspace layout (float units)
#define OFF_SEQ    ((size_t)0)          // [45][800][320] f32; later aliased by gpart/lpart
#define OFF_H      ((size_t)11520000)   // [45][800][320] f32
#define OFF_BP     ((size_t)23040000)   // [1280][960] ushort (bf16 tripled)
#define OFF_BIAS   ((size_t)23654400)   // [1280] f32
#define OFF_WD     ((size_t)23655680)   // [320][128] ushort (conv w bf16, k-padded)
#define OFF_GENE   ((size_t)23691520)   // [800][320] f32
#define OFF_STATS  ((size_t)23947520)   // [640]
#define OFF_ATTN   ((size_t)23948160)   // [45*800]
#define OFF_HID    ((size_t)23984160)   // [800][925]

typedef __attribute__((ext_vector_type(8))) short short8v;
typedef __attribute__((ext_vector_type(8))) unsigned short ushort8v;
typedef __attribute__((ext_vector_type(4))) float f32x4;

__device__ __forceinline__ float sigf(float x) { return 1.0f / (1.0f + expf(-x)); }

__device__ __forceinline__ unsigned short bf16rne(float f) {
    unsigned u = __float_as_uint(f);
    return (unsigned short)((u + 0x7fffu + ((u >> 16) & 1u)) >> 16);
}

// Truncation-based hi/lo split: f = hi + lo + O(2^-16 |f|)
__device__ __forceinline__ void split3(float f, unsigned& hi, unsigned& lo) {
    unsigned u = __float_as_uint(f);
    unsigned hu = u & 0xffff0000u;
    float d = f - __uint_as_float(hu);
    hi = u >> 16;
    lo = __float_as_uint(d) >> 16;
}

// ---------------------------------------------------------------------------
// LSTM weights: permuted n = dir*640 + jg*64 + gate*16 + jl, tripled (hi,hi,lo)
// ---------------------------------------------------------------------------
__global__ void prep_lstm_kernel(const float* __restrict__ wf, const float* __restrict__ bif,
                                 const float* __restrict__ bhf,
                                 const float* __restrict__ wb, const float* __restrict__ bib,
                                 const float* __restrict__ bhb,
                                 unsigned short* __restrict__ Bp, float* __restrict__ biasv) {
    int idx = blockIdx.x * 256 + threadIdx.x;
    if (idx < LSTM_N * LSTM_K) {
        int n = idx / LSTM_K, k = idx % LSTM_K;
        int dir = n / 640, r = n % 640;
        int jg = r >> 6, rr = r & 63, gate = rr >> 4, jl = rr & 15;
        int srow = gate * HID + jg * 16 + jl;
        const float* w = dir ? wb : wf;
        float f = w[(size_t)srow * LSTM_K + k];
        unsigned hi, lo;
        split3(f, hi, lo);
        unsigned short* d = Bp + (size_t)n * 960 + 3 * k;
        d[0] = (unsigned short)hi;
        d[1] = (unsigned short)hi;
        d[2] = (unsigned short)lo;
    }
    if (idx < LSTM_N) {
        int n = idx;
        int dir = n / 640, r = n % 640;
        int jg = r >> 6, rr = r & 63, gate = rr >> 4, jl = rr & 15;
        int srow = gate * HID + jg * 16 + jl;
        biasv[n] = dir ? (bib[srow] + bhb[srow]) : (bif[srow] + bhf[srow]);
    }
}

// ---------------------------------------------------------------------------
// Conv weights: bf16 RNE, [320][128] with k>=104 zero.
// ---------------------------------------------------------------------------
__global__ void prep_convw_kernel(const float* __restrict__ cw, unsigned short* __restrict__ wd) {
    int idx = blockIdx.x * 256 + threadIdx.x;
    if (idx < COUT * 128) {
        int c = idx >> 7, k = idx & 127;
        unsigned short v = 0;
        if (k < 104) v = bf16rne(cw[(size_t)c * 104 + k]);
        wd[idx] = v;
    }
}

// ---------------------------------------------------------------------------
// Fused Conv1d(4->320,k=26) + bias + ReLU + left-pad(14) + MaxPool(13) via MFMA.
// Block = (b, wtile of 9 pool windows = 117 positions) x 128-col ctile.
// Pure bf16 (RNE) inputs, K padded 104->128 (4 k-steps of 32).
// LDS 70912 B -> 2 blocks/CU. Stride 136 ushorts (272B): 16B-aligned, uniform
// 8-accesses/bank for all b128 ops (ds_read_b128 floor). Pool epilogue via
// f32 C-scratch reusing the As/Bs region.
// ---------------------------------------------------------------------------
#define AST 136   // ushort LDS row stride
#define CST 130   // float C-scratch row stride

__global__ __launch_bounds__(256) void conv_mfma_kernel(const float* __restrict__ x,
                                                        const unsigned short* __restrict__ wd,
                                                        const float* __restrict__ cb,
                                                        float* __restrict__ seq) {
    __shared__ __align__(16) unsigned char smem[70912];
    unsigned short* As = (unsigned short*)smem;              // [128][AST]
    unsigned short* Bs = As + 128 * AST;                     // [128][AST]
    unsigned short* xraw = Bs + 128 * AST;                   // [4][160]
    float* Cs = (float*)smem;                                // [128][CST]

    int bx = blockIdx.x;
    int b = bx / 5, wt = bx % 5;
    int col0 = blockIdx.y * 128;
    int p0 = 117 * wt - 14;
    int tid = threadIdx.x;

    // 1a. stage raw x window (bf16 RNE): positions p0 .. p0+153
    {
        const float* xb = x + (size_t)b * (CIN * XLEN);
        for (int j = tid; j < 4 * 160; j += 256) {
            int ch = j / 160, i = j - ch * 160;
            int p = p0 + i;
            float v = (i < 154 && p >= 0 && p < XLEN) ? xb[ch * XLEN + p] : 0.0f;
            xraw[ch * 160 + i] = bf16rne(v);
        }
    }
    // 1b. stage B: wd[col0+c][0..127]
#pragma unroll
    for (int i = 0; i < 8; ++i) {
        int j = i * 256 + tid;            // < 2048 = 128 rows * 16 segs
        int c = j >> 4, seg = j & 15;
        int cg = col0 + c;
        ushort8v o = {0, 0, 0, 0, 0, 0, 0, 0};
        if (cg < COUT) o = *reinterpret_cast<const ushort8v*>(wd + (size_t)cg * 128 + seg * 8);
        *reinterpret_cast<ushort8v*>(Bs + c * AST + seg * 8) = o;
    }
    __syncthreads();

    // 2. build im2col rows of A from xraw (LDS->LDS)
#pragma unroll
    for (int i = 0; i < 8; ++i) {
        int j = i * 256 + tid;            // < 2048 = 128 rows * 16 kgroups
        int r = j >> 4, kg = j & 15;
        ushort8v o = {0, 0, 0, 0, 0, 0, 0, 0};
        if (kg < 13) {                    // k < 104
#pragma unroll
            for (int e = 0; e < 8; ++e) {
                int k = kg * 8 + e;
                int ch = (k * 631) >> 14;     // k / 26 for k < 104
                int kk = k - ch * 26;
                o[e] = xraw[ch * 160 + r + kk];
            }
        }
        *reinterpret_cast<ushort8v*>(As + r * AST + kg * 8) = o;
    }
    __syncthreads();

    // 3. MFMA: 4 k-steps x (4m x 4n) frags
    const int w = tid >> 6, lane = tid & 63;
    const int wr = w >> 1, wc = w & 1;
    const int l15 = lane & 15, lq = lane >> 4;

    f32x4 acc[4][4];
#pragma unroll
    for (int m = 0; m < 4; ++m)
#pragma unroll
        for (int n = 0; n < 4; ++n) acc[m][n] = (f32x4){0.f, 0.f, 0.f, 0.f};

#pragma unroll
    for (int ks = 0; ks < 4; ++ks) {
        short8v af[4], bf[4];
#pragma unroll
        for (int m = 0; m < 4; ++m)
            af[m] = *reinterpret_cast<const short8v*>(As + (wr * 64 + m * 16 + l15) * AST + ks * 32 + lq * 8);
#pragma unroll
        for (int n = 0; n < 4; ++n)
            bf[n] = *reinterpret_cast<const short8v*>(Bs + (wc * 64 + n * 16 + l15) * AST + ks * 32 + lq * 8);
#pragma unroll
        for (int m = 0; m < 4; ++m)
#pragma unroll
            for (int n = 0; n < 4; ++n)
                acc[m][n] = __builtin_amdgcn_mfma_f32_16x16x32_bf16(af[m], bf[n], acc[m][n], 0, 0, 0);
    }
    __syncthreads();

    // 4. acc -> C scratch
#pragma unroll
    for (int m = 0; m < 4; ++m)
#pragma unroll
        for (int n = 0; n < 4; ++n)
#pragma unroll
            for (int rg = 0; rg < 4; ++rg) {
                int row = wr * 64 + m * 16 + lq * 4 + rg;
                int col = wc * 64 + n * 16 + l15;
                Cs[row * CST + col] = acc[m][n][rg];
            }
    __syncthreads();

    // 5. pool 9 windows x 128 cols (+bias, relu floor, pad exclusion)
#pragma unroll
    for (int i = 0; i < 5; ++i) {
        int j = i * 256 + tid;
        if (j < 9 * 128) {
            int u = j >> 7, c = j & 127;
            int cg = col0 + c;
            if (cg < COUT) {
                float bias = cb[cg];
                float mx = 0.0f;
#pragma unroll
                for (int jj = 0; jj < 13; ++jj) {
                    int r = 13 * u + jj;
                    int p = p0 + r;
                    if (p >= 0 && p < 575) mx = fmaxf(mx, Cs[r * CST + c] + bias);
                }
                seq[((size_t)(wt * 9 + u) * BB + b) * COUT + cg] = mx;
            }
        }
    }
}

// ---------------------------------------------------------------------------
// Split-bf16 MFMA GEMM (tile 128x128, 4 waves, K-chunk 32 -> tripled 96).
// MODE 0: split-K partials. MODE 1: LSTM activation epilogue.
// BPRE: B pre-tripled in global. AFUSE: A[r][k] = attn[t*800+r]*h[(t*800+r)][d].
// ---------------------------------------------------------------------------
__device__ __forceinline__ void load_f32_tile(const float* __restrict__ P, int ld, int r0, int R,
                                              int K, int k0, bool fast, int tid, float4* L) {
#pragma unroll
    for (int i = 0; i < 4; ++i) {
        int v = tid + i * 256;
        int r = v >> 3, kq = v & 7;
        int gr = r0 + r;
        float4 val = make_float4(0.f, 0.f, 0.f, 0.f);
        if (gr < R) {
            const float* p = P + (size_t)gr * ld + k0 + kq * 4;
            if (fast) {
                val = *reinterpret_cast<const float4*>(p);
            } else {
                int kb = k0 + kq * 4;
                if (kb + 0 < K) val.x = p[0];
                if (kb + 1 < K) val.y = p[1];
                if (kb + 2 < K) val.z = p[2];
                if (kb + 3 < K) val.w = p[3];
            }
        }
        L[i] = val;
    }
}

template <bool APAT>
__device__ __forceinline__ void write_trip_row(unsigned short* rowp, int kq, float4 val) {
    unsigned h[4], l[4];
    split3(val.x, h[0], l[0]);
    split3(val.y, h[1], l[1]);
    split3(val.z, h[2], l[2]);
    split3(val.w, h[3], l[3]);
    unsigned short t[12];
#pragma unroll
    for (int e = 0; e < 4; ++e) {
        t[3 * e + 0] = (unsigned short)h[e];
        t[3 * e + 1] = APAT ? (unsigned short)l[e] : (unsigned short)h[e];
        t[3 * e + 2] = APAT ? (unsigned short)h[e] : (unsigned short)l[e];
    }
    unsigned* d = reinterpret_cast<unsigned*>(rowp + 12 * kq);
#pragma unroll
    for (int q = 0; q < 6; ++q) d[q] = (unsigned)t[2 * q] | ((unsigned)t[2 * q + 1] << 16);
}

template <int MODE, bool BPRE, bool AFUSE>
__global__ __launch_bounds__(256) void mfma_gemm(const float* __restrict__ A, int lda,
                                                 const float* __restrict__ Bf, int ldb,
                                                 const unsigned short* __restrict__ Bp, int ldbp,
                                                 const float* __restrict__ attnp,
                                                 int M, int N, int K, int chunksPerSplit,
                                                 float* __restrict__ outp,
                                                 const float* __restrict__ biasv,
                                                 float* __restrict__ hout) {
    __shared__ unsigned short As[128][104];
    __shared__ unsigned short Bs[128][104];
    const int tid = threadIdx.x;
    const int bm = blockIdx.x, bn = blockIdx.y, sp = blockIdx.z;
    const int row0 = bm * 128, col0 = bn * 128;
    const int totChunks = (K + 31) >> 5;
    const int c_beg = sp * chunksPerSplit;
    const int c_end = min(totChunks, c_beg + chunksPerSplit);

    const int w = tid >> 6, lane = tid & 63;
    const int wr = w >> 1, wc = w & 1;
    const int l15 = lane & 15, lq = lane >> 4;

    f32x4 acc[4][4];
#pragma unroll
    for (int m = 0; m < 4; ++m)
#pragma unroll
        for (int n = 0; n < 4; ++n) acc[m][n] = (f32x4){0.f, 0.f, 0.f, 0.f};

    float4 aL[4];
    float4 bL[4];
    ushort8v bP[6];

    auto loadA = [&](int k0) {
        if (AFUSE) {
            int t = k0 / 320;
            int d0 = k0 - t * 320;
            const float* hb = A + (size_t)t * (BB * 320);
            const float* ab = attnp + t * BB;
#pragma unroll
            for (int i = 0; i < 4; ++i) {
                int v = tid + i * 256;
                int r = v >> 3, kq = v & 7;
                int gr = row0 + r;
                float4 val = make_float4(0.f, 0.f, 0.f, 0.f);
                if (gr < M) {
                    val = *reinterpret_cast<const float4*>(hb + (size_t)gr * 320 + d0 + kq * 4);
                    float aw = ab[gr];
                    val.x *= aw; val.y *= aw; val.z *= aw; val.w *= aw;
                }
                aL[i] = val;
            }
        } else {
            bool fastA = ((lda & 3) == 0) && (k0 + 32 <= K);
            load_f32_tile(A, lda, row0, M, K, k0, fastA, tid, aL);
        }
    };
    auto loadB = [&](int c) {
        if (!BPRE) {
            int k0 = c * 32;
            bool fastB = ((ldb & 3) == 0) && (k0 + 32 <= K);
            load_f32_tile(Bf, ldb, col0, N, K, k0, fastB, tid, bL);
        } else {
#pragma unroll
            for (int i = 0; i < 6; ++i) {
                int v = tid + i * 256;
                int r = v / 12, seg = v - r * 12;
                int gc = col0 + r;
                ushort8v z = {0, 0, 0, 0, 0, 0, 0, 0};
                bP[i] = (gc < N) ? *reinterpret_cast<const ushort8v*>(
                                       Bp + (size_t)gc * ldbp + (size_t)c * 96 + seg * 8)
                                 : z;
            }
        }
    };

    loadA(c_beg * 32);
    loadB(c_beg);

    for (int c = c_beg; c < c_end; ++c) {
        __syncthreads();
#pragma unroll
        for (int i = 0; i < 4; ++i) {
            int v = tid + i * 256;
            int r = v >> 3, kq = v & 7;
            write_trip_row<true>(&As[r][0], kq, aL[i]);
        }
        if (!BPRE) {
#pragma unroll
            for (int i = 0; i < 4; ++i) {
                int v = tid + i * 256;
                int r = v >> 3, kq = v & 7;
                write_trip_row<false>(&Bs[r][0], kq, bL[i]);
            }
        } else {
#pragma unroll
            for (int i = 0; i < 6; ++i) {
                int v = tid + i * 256;
                int r = v / 12, seg = v - r * 12;
                *reinterpret_cast<ushort8v*>(&Bs[r][seg * 8]) = bP[i];
            }
        }
        __syncthreads();

        if (c + 1 < c_end) {
            loadA((c + 1) * 32);
            loadB(c + 1);
        }

#pragma unroll
        for (int ks = 0; ks < 3; ++ks) {
            short8v af[4], bf4[4];
#pragma unroll
            for (int m = 0; m < 4; ++m)
                af[m] = *reinterpret_cast<const short8v*>(&As[wr * 64 + m * 16 + l15][ks * 32 + lq * 8]);
#pragma unroll
            for (int n = 0; n < 4; ++n)
                bf4[n] = *reinterpret_cast<const short8v*>(&Bs[wc * 64 + n * 16 + l15][ks * 32 + lq * 8]);
#pragma unroll
            for (int m = 0; m < 4; ++m)
#pragma unroll
                for (int n = 0; n < 4; ++n)
                    acc[m][n] = __builtin_amdgcn_mfma_f32_16x16x32_bf16(af[m], bf4[n], acc[m][n], 0, 0, 0);
        }
    }

    if (MODE == 0) {
#pragma unroll
        for (int m = 0; m < 4; ++m)
#pragma unroll
            for (int n = 0; n < 4; ++n)
#pragma unroll
                for (int rg = 0; rg < 4; ++rg) {
                    int row_g = row0 + wr * 64 + m * 16 + lq * 4 + rg;
                    int col_g = col0 + wc * 64 + n * 16 + l15;
                    if (row_g < M && col_g < N)
                        outp[((size_t)sp * M + row_g) * N + col_g] = acc[m][n][rg];
                }
    } else {
        int c0 = col0 + wc * 64;
        int dir = c0 / 640;
        int jgl = (c0 % 640) >> 6;
        int hcol = dir * HID + jgl * 16 + l15;
        float bi = biasv[c0 + l15];
        float bg = biasv[c0 + 32 + l15];
        float bo = biasv[c0 + 48 + l15];
#pragma unroll
        for (int m = 0; m < 4; ++m)
#pragma unroll
            for (int rg = 0; rg < 4; ++rg) {
                int row_g = row0 + wr * 64 + m * 16 + lq * 4 + rg;
                if (row_g >= M) continue;
                float gi = acc[m][0][rg] + bi;
                float gg = acc[m][2][rg] + bg;
                float go = acc[m][3][rg] + bo;
                float cc = sigf(gi) * tanhf(gg);
                hout[(size_t)row_g * 320 + hcol] = sigf(go) * tanhf(cc);
            }
    }
}

// ---------------------------------------------------------------------------
__global__ void gene_reduce_kernel(const float* __restrict__ part, const float* __restrict__ gene_b,
                                   float* __restrict__ out) {
    int idx = blockIdx.x * 256 + threadIdx.x;
    if (idx >= BB * GENE_N) return;
    int n = idx % GENE_N;
    float sum = gene_b[n];
#pragma unroll
    for (int ss = 0; ss < GENE_SPLITS; ++ss) sum += part[(size_t)ss * (BB * GENE_N) + idx];
    out[idx] = sum;
}

__global__ void bn_stats_kernel(const float* __restrict__ g, float* __restrict__ stats) {
    int n = blockIdx.x;
    int tid = threadIdx.x;
    float s = 0.0f, s2 = 0.0f;
    for (int m = tid; m < BB; m += 256) {
        float v = g[(size_t)m * GENE_N + n];
        s += v;
        s2 += v * v;
    }
    __shared__ float red0[256], red1[256];
    red0[tid] = s; red1[tid] = s2;
    __syncthreads();
    for (int off = 128; off; off >>= 1) {
        if (tid < off) { red0[tid] += red0[tid + off]; red1[tid] += red1[tid + off]; }
        __syncthreads();
    }
    if (tid == 0) {
        float mean = red0[0] / (float)BB;
        float var = red1[0] / (float)BB - mean * mean;
        stats[n] = mean;
        stats[GENE_N + n] = rsqrtf(var + 1e-5f);
    }
}

__global__ void bn_apply_kernel(float* __restrict__ g, const float* __restrict__ stats,
                                const float* __restrict__ gamma, const float* __restrict__ beta) {
    int idx = blockIdx.x * 256 + threadIdx.x;
    if (idx >= BB * GENE_N) return;
    int n = idx % GENE_N;
    float v = (g[idx] - stats[n]) * stats[GENE_N + n] * gamma[n] + beta[n];
    g[idx] = fmaxf(v, 0.0f);
}

__global__ void attn_kernel(const float* __restrict__ h, const float* __restrict__ gene,
                            float* __restrict__ attn) {
    int r = blockIdx.x;
    int b = r % BB;
    int lane = threadIdx.x;
    const float* hr = h + (size_t)r * 320;
    const float* gr = gene + (size_t)b * 320;
    float s = 0.0f;
    for (int d = lane; d < 320; d += 64) s += hr[d] * gr[d];
    for (int off = 32; off; off >>= 1) s += __shfl_down(s, off);
    if (lane == 0) attn[r] = s;
}

__global__ void lin_reduce_kernel(const float* __restrict__ part, const float* __restrict__ lin_b,
                                  float* __restrict__ hid) {
    int idx = blockIdx.x * 256 + threadIdx.x;
    if (idx >= BB * LIN_N) return;
    int n = idx % LIN_N;
    float sum = lin_b[n];
#pragma unroll
    for (int ss = 0; ss < LIN_SPLITS; ++ss) sum += part[(size_t)ss * (BB * LIN_N) + idx];
    hid[idx] = fmaxf(sum, 0.0f);
}

__global__ void out_kernel(const float* __restrict__ hid, const float* __restrict__ ow,
                           const float* __restrict__ ob, float* __restrict__ out) {
    int b = blockIdx.x;
    int lane = threadIdx.x;
    float s = 0.0f;
    for (int n = lane; n < LIN_N; n += 64) s += hid[(size_t)b * LIN_N + n] * ow[n];
    for (int off = 32; off; off >>= 1) s += __shfl_down(s, off);
    if (lane == 0) out[b] = s + ob[0];
}

// ---------------------------------------------------------------------------
extern "C" void kernel_launch(void* const* d_in, const int* in_sizes, int n_in,
                              void* d_out, int out_size, void* d_ws, size_t ws_size,
                              hipStream_t stream) {
    const float* x        = (const float*)d_in[0];
    const float* geneexpr = (const float*)d_in[1];
    const float* conv_w   = (const float*)d_in[2];
    const float* conv_b   = (const float*)d_in[3];
    const float* w_ih_f   = (const float*)d_in[4];
    const float* b_ih_f   = (const float*)d_in[5];
    const float* b_hh_f   = (const float*)d_in[6];
    const float* w_ih_b   = (const float*)d_in[7];
    const float* b_ih_b   = (const float*)d_in[8];
    const float* b_hh_b   = (const float*)d_in[9];
    const float* gene_w   = (const float*)d_in[10];
    const float* gene_b   = (const float*)d_in[11];
    const float* bn_gamma = (const float*)d_in[12];
    const float* bn_beta  = (const float*)d_in[13];
    const float* lin_w    = (const float*)d_in[14];
    const float* lin_b    = (const float*)d_in[15];
    const float* out_w    = (const float*)d_in[16];
    const float* out_b    = (const float*)d_in[17];

    float* ws  = (float*)d_ws;
    float* out = (float*)d_out;

    float* seq            = ws + OFF_SEQ;
    float* h              = ws + OFF_H;
    unsigned short* Bp    = (unsigned short*)(ws + OFF_BP);
    float* biasv          = ws + OFF_BIAS;
    unsigned short* wd    = (unsigned short*)(ws + OFF_WD);
    float* gene           = ws + OFF_GENE;
    float* stats          = ws + OFF_STATS;
    float* attn           = ws + OFF_ATTN;
    float* hid            = ws + OFF_HID;
    float* gpart          = ws + OFF_SEQ;   // alias (seq dead after LSTM GEMM)
    float* lpart          = ws + OFF_SEQ;   // alias (gpart dead after gene_reduce)

    // 1. LSTM weights triple + bias ; conv weights bf16
    prep_lstm_kernel<<<1600, 256, 0, stream>>>(w_ih_f, b_ih_f, b_hh_f,
                                               w_ih_b, b_ih_b, b_hh_b, Bp, biasv);
    prep_convw_kernel<<<160, 256, 0, stream>>>(conv_w, wd);
    // 2. fused conv+bias+relu+pad+pool via MFMA -> seq
    conv_mfma_kernel<<<dim3(BB * 5, 3, 1), 256, 0, stream>>>(x, wd, conv_b, seq);
    // 3. LSTM gates MFMA GEMM + activation epilogue -> h
    mfma_gemm<1, true, false><<<dim3(282, 10, 1), 256, 0, stream>>>(
        seq, LSTM_K, nullptr, 0, Bp, 960, nullptr, LSTM_M, LSTM_N, LSTM_K, 10,
        nullptr, biasv, h);
    // 4. gene MFMA GEMM (split-K 31, 20 chunks each)
    mfma_gemm<0, false, false><<<dim3(7, 3, GENE_SPLITS), 256, 0, stream>>>(
        geneexpr, GENE_K, gene_w, GENE_K, nullptr, 0, nullptr, BB, GENE_N, GENE_K, 20,
        gpart, nullptr, nullptr);
    // 5. reduce + bias
    gene_reduce_kernel<<<1000, 256, 0, stream>>>(gpart, gene_b, gene);
    // 6-7. BN
    bn_stats_kernel<<<GENE_N, 256, 0, stream>>>(gene, stats);
    bn_apply_kernel<<<1000, 256, 0, stream>>>(gene, stats, bn_gamma, bn_beta);
    // 8. attention scores
    attn_kernel<<<LSTM_M, 64, 0, stream>>>(h, gene, attn);
    // 9. lin MFMA GEMM (split-K 8, 57 chunks), A fused = attn*h on the fly
    mfma_gemm<0, false, true><<<dim3(7, 8, LIN_SPLITS), 256, 0, stream>>>(
        h, 320, lin_w, LIN_K, nullptr, 0, attn, BB, LIN_N, LIN_K, 57,
        lpart, nullptr, nullptr);
    // 10. reduce + bias + relu
    lin_reduce_kernel<<<2891, 256, 0, stream>>>(lpart, lin_b, hid);
    // 11. final dot
    out_kernel<<<BB, 64, 0, stream>>>(hid, out_w, out_b, out);
}

// Round 7
// 553.152 us; speedup vs baseline: 6.7256x; 1.6057x over previous
//
#include <hip/hip_runtime.h>
#include <hip/hip_bf16.h>
#include <math.h>

// Problem constants
#define BB   800
#define CIN  4
#define XLEN 600
#define COUT 320
#define KW   26
#define TT   45
#define HID  160
#define LSTM_N 1280          // 2 dirs * [jg(10) x gate(4) x jl(16)] permuted
#define LSTM_K 320
#define LSTM_M 36000
#define GENE_K 19795
#define GENE_KP 19840        // padded to 64
#define GENE_N 320
#define LIN_K 14400
#define LIN_N 925
#define GENE_SPLITS 16
#define LIN_SPLITS 8

// Workspace layout (float units)
#define OFF_SEQS   ((size_t)0)          // [36000][640] ush (hi|lo) ; later gpart/lpart alias
#define OFF_H      ((size_t)11520000)   // [36000][320] ush bf16
#define OFF_BP     ((size_t)17280000)   // [1280][320] ush bf16 (permuted LSTM w)
#define OFF_BIAS   ((size_t)17484800)   // [1280] f32
#define OFF_WD     ((size_t)17486080)   // [320][128] ush (conv w bf16, k-padded)
#define OFF_GENEW  ((size_t)17506560)   // [320][19840] ush bf16
#define OFF_LINW   ((size_t)20680960)   // [925][14400] ush bf16
#define OFF_GENE   ((size_t)27340960)   // [800][320] f32
#define OFF_STATS  ((size_t)27596960)   // [640]
#define OFF_ATTN   ((size_t)27597600)   // [45*800]
#define OFF_HID    ((size_t)27633600)   // [800][925]

typedef __attribute__((ext_vector_type(8))) short short8v;
typedef __attribute__((ext_vector_type(8))) unsigned short ushort8v;
typedef __attribute__((ext_vector_type(4))) float f32x4;

__device__ __forceinline__ float sigf(float x) { return 1.0f / (1.0f + expf(-x)); }

__device__ __forceinline__ unsigned short bf16rne(float f) {
    unsigned u = __float_as_uint(f);
    return (unsigned short)((u + 0x7fffu + ((u >> 16) & 1u)) >> 16);
}
__device__ __forceinline__ float bf2f(unsigned short u) {
    return __uint_as_float((unsigned)u << 16);
}
// Truncation-based hi/lo split: f = hi + lo + O(2^-16 |f|)
__device__ __forceinline__ void split3(float f, unsigned& hi, unsigned& lo) {
    unsigned u = __float_as_uint(f);
    unsigned hu = u & 0xffff0000u;
    float d = f - __uint_as_float(hu);
    hi = u >> 16;
    lo = __float_as_uint(d) >> 16;
}

// ---------------------------------------------------------------------------
// Prep kernels: weights -> plain bf16 (RNE)
// ---------------------------------------------------------------------------
__global__ void prep_lstm_kernel(const float* __restrict__ wf, const float* __restrict__ bif,
                                 const float* __restrict__ bhf,
                                 const float* __restrict__ wb, const float* __restrict__ bib,
                                 const float* __restrict__ bhb,
                                 unsigned short* __restrict__ Bp, float* __restrict__ biasv) {
    int idx = blockIdx.x * 256 + threadIdx.x;
    if (idx < LSTM_N * LSTM_K) {
        int n = idx / LSTM_K, k = idx % LSTM_K;
        int dir = n / 640, r = n % 640;
        int jg = r >> 6, rr = r & 63, gate = rr >> 4, jl = rr & 15;
        int srow = gate * HID + jg * 16 + jl;
        const float* w = dir ? wb : wf;
        Bp[idx] = bf16rne(w[(size_t)srow * LSTM_K + k]);
    }
    if (idx < LSTM_N) {
        int n = idx;
        int dir = n / 640, r = n % 640;
        int jg = r >> 6, rr = r & 63, gate = rr >> 4, jl = rr & 15;
        int srow = gate * HID + jg * 16 + jl;
        biasv[n] = dir ? (bib[srow] + bhb[srow]) : (bif[srow] + bhf[srow]);
    }
}

__global__ void prep_convw_kernel(const float* __restrict__ cw, unsigned short* __restrict__ wd) {
    int idx = blockIdx.x * 256 + threadIdx.x;
    if (idx < COUT * 128) {
        int c = idx >> 7, k = idx & 127;
        wd[idx] = (k < 104) ? bf16rne(cw[(size_t)c * 104 + k]) : (unsigned short)0;
    }
}

__global__ void prep_genew_kernel(const float* __restrict__ gw, unsigned short* __restrict__ o) {
    int idx = blockIdx.x * 256 + threadIdx.x;
    if (idx < GENE_N * GENE_KP) {
        int c = idx / GENE_KP, k = idx % GENE_KP;
        o[idx] = (k < GENE_K) ? bf16rne(gw[(size_t)c * GENE_K + k]) : (unsigned short)0;
    }
}

__global__ void prep_linw_kernel(const float* __restrict__ lw, unsigned short* __restrict__ o) {
    int idx = blockIdx.x * 256 + threadIdx.x;
    if (idx < LIN_N * LIN_K) o[idx] = bf16rne(lw[idx]);
}

// ---------------------------------------------------------------------------
// Fused Conv1d + bias + ReLU + pad + MaxPool via MFMA (round-5 structure).
// Epilogue writes seq pre-split: seqs[row][c] = hi, seqs[row][320+c] = lo.
// ---------------------------------------------------------------------------
#define AST 136
#define CST 130

__global__ __launch_bounds__(256) void conv_mfma_kernel(const float* __restrict__ x,
                                                        const unsigned short* __restrict__ wd,
                                                        const float* __restrict__ cb,
                                                        unsigned short* __restrict__ seqs) {
    __shared__ __align__(16) unsigned char smem[70912];
    unsigned short* As = (unsigned short*)smem;              // [128][AST]
    unsigned short* Bs = As + 128 * AST;                     // [128][AST]
    unsigned short* xraw = Bs + 128 * AST;                   // [4][160]
    float* Cs = (float*)smem;                                // [128][CST]

    int bx = blockIdx.x;
    int b = bx / 5, wt = bx % 5;
    int col0 = blockIdx.y * 128;
    int p0 = 117 * wt - 14;
    int tid = threadIdx.x;

    {
        const float* xb = x + (size_t)b * (CIN * XLEN);
        for (int j = tid; j < 4 * 160; j += 256) {
            int ch = j / 160, i = j - ch * 160;
            int p = p0 + i;
            float v = (i < 154 && p >= 0 && p < XLEN) ? xb[ch * XLEN + p] : 0.0f;
            xraw[ch * 160 + i] = bf16rne(v);
        }
    }
#pragma unroll
    for (int i = 0; i < 8; ++i) {
        int j = i * 256 + tid;
        int c = j >> 4, seg = j & 15;
        int cg = col0 + c;
        ushort8v o = {0, 0, 0, 0, 0, 0, 0, 0};
        if (cg < COUT) o = *reinterpret_cast<const ushort8v*>(wd + (size_t)cg * 128 + seg * 8);
        *reinterpret_cast<ushort8v*>(Bs + c * AST + seg * 8) = o;
    }
    __syncthreads();

#pragma unroll
    for (int i = 0; i < 8; ++i) {
        int j = i * 256 + tid;
        int r = j >> 4, kg = j & 15;
        ushort8v o = {0, 0, 0, 0, 0, 0, 0, 0};
        if (kg < 13) {
#pragma unroll
            for (int e = 0; e < 8; ++e) {
                int k = kg * 8 + e;
                int ch = (k * 631) >> 14;
                int kk = k - ch * 26;
                o[e] = xraw[ch * 160 + r + kk];
            }
        }
        *reinterpret_cast<ushort8v*>(As + r * AST + kg * 8) = o;
    }
    __syncthreads();

    const int w = tid >> 6, lane = tid & 63;
    const int wr = w >> 1, wc = w & 1;
    const int l15 = lane & 15, lq = lane >> 4;

    f32x4 acc[4][4];
#pragma unroll
    for (int m = 0; m < 4; ++m)
#pragma unroll
        for (int n = 0; n < 4; ++n) acc[m][n] = (f32x4){0.f, 0.f, 0.f, 0.f};

#pragma unroll
    for (int ks = 0; ks < 4; ++ks) {
        short8v af[4], bf[4];
#pragma unroll
        for (int m = 0; m < 4; ++m)
            af[m] = *reinterpret_cast<const short8v*>(As + (wr * 64 + m * 16 + l15) * AST + ks * 32 + lq * 8);
#pragma unroll
        for (int n = 0; n < 4; ++n)
            bf[n] = *reinterpret_cast<const short8v*>(Bs + (wc * 64 + n * 16 + l15) * AST + ks * 32 + lq * 8);
#pragma unroll
        for (int m = 0; m < 4; ++m)
#pragma unroll
            for (int n = 0; n < 4; ++n)
                acc[m][n] = __builtin_amdgcn_mfma_f32_16x16x32_bf16(af[m], bf[n], acc[m][n], 0, 0, 0);
    }
    __syncthreads();

#pragma unroll
    for (int m = 0; m < 4; ++m)
#pragma unroll
        for (int n = 0; n < 4; ++n)
#pragma unroll
            for (int rg = 0; rg < 4; ++rg) {
                int row = wr * 64 + m * 16 + lq * 4 + rg;
                int col = wc * 64 + n * 16 + l15;
                Cs[row * CST + col] = acc[m][n][rg];
            }
    __syncthreads();

#pragma unroll
    for (int i = 0; i < 5; ++i) {
        int j = i * 256 + tid;
        if (j < 9 * 128) {
            int u = j >> 7, c = j & 127;
            int cg = col0 + c;
            if (cg < COUT) {
                float bias = cb[cg];
                float mx = 0.0f;
#pragma unroll
                for (int jj = 0; jj < 13; ++jj) {
                    int r = 13 * u + jj;
                    int p = p0 + r;
                    if (p >= 0 && p < 575) mx = fmaxf(mx, Cs[r * CST + c] + bias);
                }
                unsigned hi, lo;
                split3(mx, hi, lo);
                size_t rowi = (size_t)(wt * 9 + u) * BB + b;
                seqs[rowi * 640 + cg] = (unsigned short)hi;
                seqs[rowi * 640 + 320 + cg] = (unsigned short)lo;
            }
        }
    }
}

// ---------------------------------------------------------------------------
// gemm2: two-pass doubled GEMM. out[r][n] = sum_k A[r][k] * bf16(B[n][k]).
// A staged as [hi 64 | lo 64] ush per 64-k chunk; B plain bf16 [N][Kpad].
// MFMA: per ks(2): load B-frag once; pass0 uses A-hi, pass1 A-lo.
// VAR 0 = LSTM (A pre-split [M][640], epilogue -> h bf16, XCD grid)
// VAR 1 = gene (A f32 scalar-masked loads, split on the fly, split-K 16)
// VAR 2 = lin  (A = attn[t,r] * h_bf16, split on the fly, split-K 8)
// ---------------------------------------------------------------------------
template <int VAR>
__global__ __launch_bounds__(256) void gemm2(const unsigned short* __restrict__ Apre,
                                             const float* __restrict__ Af32, int lda,
                                             const unsigned short* __restrict__ Bn, int ldb,
                                             const float* __restrict__ attnp,
                                             int M, int N, int Kreal,
                                             int totChunks, int cps,
                                             float* __restrict__ outp,
                                             const float* __restrict__ biasv,
                                             unsigned short* __restrict__ hout) {
    __shared__ unsigned short Al[128][136];
    __shared__ unsigned short Bl[128][72];
    const int tid = threadIdx.x;

    int bm, bn, sp;
    if (VAR == 0) {
        int xcd = blockIdx.x;
        bn = blockIdx.y % 10;
        bm = xcd + 8 * (blockIdx.y / 10);
        sp = 0;
        if (bm >= 282) return;
    } else if (VAR == 1) {
        int xcd = blockIdx.x;
        sp = xcd + 8 * (blockIdx.y / 21);
        int r = blockIdx.y % 21;
        bm = r / 3; bn = r % 3;
    } else {
        sp = blockIdx.x;
        bn = blockIdx.y / 7; bm = blockIdx.y % 7;
    }
    const int row0 = bm * 128, col0 = bn * 128;
    const int c_beg = sp * cps;
    const int c_end = min(totChunks, c_beg + cps);

    const int w = tid >> 6, lane = tid & 63;
    const int wr = w >> 1, wc = w & 1;
    const int l15 = lane & 15, lq = lane >> 4;

    f32x4 acc[4][4];
#pragma unroll
    for (int m = 0; m < 4; ++m)
#pragma unroll
        for (int n = 0; n < 4; ++n) acc[m][n] = (f32x4){0.f, 0.f, 0.f, 0.f};

    ushort8v aP[8];      // VAR0 raw, VAR2 raw h
    float4 aF[8];        // VAR1 raw f32
    float aW[4];         // VAR2 attn weights
    ushort8v bP[4];

    auto loadA = [&](int c) {
        int k0 = c * 64;
        if (VAR == 0) {
#pragma unroll
            for (int i = 0; i < 8; ++i) {
                int j = tid + i * 256;
                int r = j >> 4, cg = j & 15;
                int gr = row0 + r;
                ushort8v z = {0, 0, 0, 0, 0, 0, 0, 0};
                if (gr < M) {
                    int colu = (cg < 8) ? (k0 + cg * 8) : (320 + k0 + (cg - 8) * 8);
                    z = *reinterpret_cast<const ushort8v*>(Apre + (size_t)gr * 640 + colu);
                }
                aP[i] = z;
            }
        } else if (VAR == 1) {
#pragma unroll
            for (int i = 0; i < 4; ++i) {
                int j = tid + i * 256;
                int r = j >> 3, kg = j & 7;
                int gr = row0 + r;
                float4 v0 = make_float4(0.f, 0.f, 0.f, 0.f);
                float4 v1 = make_float4(0.f, 0.f, 0.f, 0.f);
                if (gr < M) {
                    int kb = k0 + kg * 8;
                    const float* p = Af32 + (size_t)gr * lda + kb;
                    if (kb + 0 < Kreal) v0.x = p[0];
                    if (kb + 1 < Kreal) v0.y = p[1];
                    if (kb + 2 < Kreal) v0.z = p[2];
                    if (kb + 3 < Kreal) v0.w = p[3];
                    if (kb + 4 < Kreal) v1.x = p[4];
                    if (kb + 5 < Kreal) v1.y = p[5];
                    if (kb + 6 < Kreal) v1.z = p[6];
                    if (kb + 7 < Kreal) v1.w = p[7];
                }
                aF[2 * i] = v0; aF[2 * i + 1] = v1;
            }
        } else {
            int t = k0 / 320, d0 = k0 - t * 320;
#pragma unroll
            for (int i = 0; i < 4; ++i) {
                int j = tid + i * 256;
                int r = j >> 3, kg = j & 7;
                int gr = row0 + r;
                ushort8v z = {0, 0, 0, 0, 0, 0, 0, 0};
                float aw = 0.0f;
                if (gr < M) {
                    z = *reinterpret_cast<const ushort8v*>(
                        Apre + ((size_t)t * BB + gr) * 320 + d0 + kg * 8);
                    aw = attnp[t * BB + gr];
                }
                aP[i] = z; aW[i] = aw;
            }
        }
    };
    auto loadB = [&](int c) {
        int k0 = c * 64;
#pragma unroll
        for (int i = 0; i < 4; ++i) {
            int j = tid + i * 256;
            int r = j >> 3, sg = j & 7;
            int gc = col0 + r;
            ushort8v z = {0, 0, 0, 0, 0, 0, 0, 0};
            if (gc < N) z = *reinterpret_cast<const ushort8v*>(Bn + (size_t)gc * ldb + k0 + sg * 8);
            bP[i] = z;
        }
    };
    auto writeAB = [&]() {
        if (VAR == 0) {
#pragma unroll
            for (int i = 0; i < 8; ++i) {
                int j = tid + i * 256;
                int r = j >> 4, cg = j & 15;
                *reinterpret_cast<ushort8v*>(&Al[r][cg * 8]) = aP[i];
            }
        } else {
#pragma unroll
            for (int i = 0; i < 4; ++i) {
                int j = tid + i * 256;
                int r = j >> 3, kg = j & 7;
                float f[8];
                if (VAR == 1) {
                    f[0] = aF[2 * i].x; f[1] = aF[2 * i].y; f[2] = aF[2 * i].z; f[3] = aF[2 * i].w;
                    f[4] = aF[2 * i + 1].x; f[5] = aF[2 * i + 1].y; f[6] = aF[2 * i + 1].z; f[7] = aF[2 * i + 1].w;
                } else {
#pragma unroll
                    for (int e = 0; e < 8; ++e) f[e] = bf2f(aP[i][e]) * aW[i];
                }
                ushort8v hv, lv;
#pragma unroll
                for (int e = 0; e < 8; ++e) {
                    unsigned hh, ll;
                    split3(f[e], hh, ll);
                    hv[e] = (unsigned short)hh; lv[e] = (unsigned short)ll;
                }
                *reinterpret_cast<ushort8v*>(&Al[r][kg * 8]) = hv;
                *reinterpret_cast<ushort8v*>(&Al[r][64 + kg * 8]) = lv;
            }
        }
#pragma unroll
        for (int i = 0; i < 4; ++i) {
            int j = tid + i * 256;
            int r = j >> 3, sg = j & 7;
            *reinterpret_cast<ushort8v*>(&Bl[r][sg * 8]) = bP[i];
        }
    };

    loadA(c_beg); loadB(c_beg);

    for (int c = c_beg; c < c_end; ++c) {
        __syncthreads();
        writeAB();
        __syncthreads();
        if (c + 1 < c_end) { loadA(c + 1); loadB(c + 1); }

#pragma unroll
        for (int ks = 0; ks < 2; ++ks) {
            short8v bf[4];
#pragma unroll
            for (int n = 0; n < 4; ++n)
                bf[n] = *reinterpret_cast<const short8v*>(&Bl[wc * 64 + n * 16 + l15][ks * 32 + lq * 8]);
#pragma unroll
            for (int pass = 0; pass < 2; ++pass) {
                short8v af[4];
#pragma unroll
                for (int m = 0; m < 4; ++m)
                    af[m] = *reinterpret_cast<const short8v*>(
                        &Al[wr * 64 + m * 16 + l15][pass * 64 + ks * 32 + lq * 8]);
#pragma unroll
                for (int m = 0; m < 4; ++m)
#pragma unroll
                    for (int n = 0; n < 4; ++n)
                        acc[m][n] = __builtin_amdgcn_mfma_f32_16x16x32_bf16(af[m], bf[n], acc[m][n], 0, 0, 0);
            }
        }
    }

    if (VAR != 0) {
#pragma unroll
        for (int m = 0; m < 4; ++m)
#pragma unroll
            for (int n = 0; n < 4; ++n)
#pragma unroll
                for (int rg = 0; rg < 4; ++rg) {
                    int row_g = row0 + wr * 64 + m * 16 + lq * 4 + rg;
                    int col_g = col0 + wc * 64 + n * 16 + l15;
                    if (row_g < M && col_g < N)
                        outp[((size_t)sp * M + row_g) * N + col_g] = acc[m][n][rg];
                }
    } else {
        int c0 = col0 + wc * 64;
        int dir = c0 / 640;
        int jgl = (c0 % 640) >> 6;
        int hcol = dir * HID + jgl * 16 + l15;
        float bi = biasv[c0 + l15];
        float bg = biasv[c0 + 32 + l15];
        float bo = biasv[c0 + 48 + l15];
#pragma unroll
        for (int m = 0; m < 4; ++m)
#pragma unroll
            for (int rg = 0; rg < 4; ++rg) {
                int row_g = row0 + wr * 64 + m * 16 + lq * 4 + rg;
                if (row_g >= M) continue;
                float gi = acc[m][0][rg] + bi;
                float gg = acc[m][2][rg] + bg;
                float go = acc[m][3][rg] + bo;
                float cc = sigf(gi) * tanhf(gg);
                hout[(size_t)row_g * 320 + hcol] = bf16rne(sigf(go) * tanhf(cc));
            }
    }
}

// ---------------------------------------------------------------------------
__global__ void gene_reduce_kernel(const float* __restrict__ part, const float* __restrict__ gene_b,
                                   float* __restrict__ out) {
    int idx = blockIdx.x * 256 + threadIdx.x;
    if (idx >= BB * GENE_N) return;
    int n = idx % GENE_N;
    float sum = gene_b[n];
#pragma unroll
    for (int ss = 0; ss < GENE_SPLITS; ++ss) sum += part[(size_t)ss * (BB * GENE_N) + idx];
    out[idx] = sum;
}

__global__ void bn_stats_kernel(const float* __restrict__ g, float* __restrict__ stats) {
    int n = blockIdx.x;
    int tid = threadIdx.x;
    float s = 0.0f, s2 = 0.0f;
    for (int m = tid; m < BB; m += 256) {
        float v = g[(size_t)m * GENE_N + n];
        s += v; s2 += v * v;
    }
    __shared__ float red0[256], red1[256];
    red0[tid] = s; red1[tid] = s2;
    __syncthreads();
    for (int off = 128; off; off >>= 1) {
        if (tid < off) { red0[tid] += red0[tid + off]; red1[tid] += red1[tid + off]; }
        __syncthreads();
    }
    if (tid == 0) {
        float mean = red0[0] / (float)BB;
        float var = red1[0] / (float)BB - mean * mean;
        stats[n] = mean;
        stats[GENE_N + n] = rsqrtf(var + 1e-5f);
    }
}

__global__ void bn_apply_kernel(float* __restrict__ g, const float* __restrict__ stats,
                                const float* __restrict__ gamma, const float* __restrict__ beta) {
    int idx = blockIdx.x * 256 + threadIdx.x;
    if (idx >= BB * GENE_N) return;
    int n = idx % GENE_N;
    float v = (g[idx] - stats[n]) * stats[GENE_N + n] * gamma[n] + beta[n];
    g[idx] = fmaxf(v, 0.0f);
}

__global__ void attn_kernel(const unsigned short* __restrict__ h, const float* __restrict__ gene,
                            float* __restrict__ attn) {
    int r = blockIdx.x;
    int b = r % BB;
    int lane = threadIdx.x;
    const unsigned short* hr = h + (size_t)r * 320;
    const float* gr = gene + (size_t)b * 320;
    float s = 0.0f;
    for (int d = lane; d < 320; d += 64) s += bf2f(hr[d]) * gr[d];
    for (int off = 32; off; off >>= 1) s += __shfl_down(s, off);
    if (lane == 0) attn[r] = s;
}

__global__ void lin_reduce_kernel(const float* __restrict__ part, const float* __restrict__ lin_b,
                                  float* __restrict__ hid) {
    int idx = blockIdx.x * 256 + threadIdx.x;
    if (idx >= BB * LIN_N) return;
    int n = idx % LIN_N;
    float sum = lin_b[n];
#pragma unroll
    for (int ss = 0; ss < LIN_SPLITS; ++ss) sum += part[(size_t)ss * (BB * LIN_N) + idx];
    hid[idx] = fmaxf(sum, 0.0f);
}

__global__ void out_kernel(const float* __restrict__ hid, const float* __restrict__ ow,
                           const float* __restrict__ ob, float* __restrict__ out) {
    int b = blockIdx.x;
    int lane = threadIdx.x;
    float s = 0.0f;
    for (int n = lane; n < LIN_N; n += 64) s += hid[(size_t)b * LIN_N + n] * ow[n];
    for (int off = 32; off; off >>= 1) s += __shfl_down(s, off);
    if (lane == 0) out[b] = s + ob[0];
}

// ---------------------------------------------------------------------------
extern "C" void kernel_launch(void* const* d_in, const int* in_sizes, int n_in,
                              void* d_out, int out_size, void* d_ws, size_t ws_size,
                              hipStream_t stream) {
    const float* x        = (const float*)d_in[0];
    const float* geneexpr = (const float*)d_in[1];
    const float* conv_w   = (const float*)d_in[2];
    const float* conv_b   = (const float*)d_in[3];
    const float* w_ih_f   = (const float*)d_in[4];
    const float* b_ih_f   = (const float*)d_in[5];
    const float* b_hh_f   = (const float*)d_in[6];
    const float* w_ih_b   = (const float*)d_in[7];
    const float* b_ih_b   = (const float*)d_in[8];
    const float* b_hh_b   = (const float*)d_in[9];
    const float* gene_w   = (const float*)d_in[10];
    const float* gene_b   = (const float*)d_in[11];
    const float* bn_gamma = (const float*)d_in[12];
    const float* bn_beta  = (const float*)d_in[13];
    const float* lin_w    = (const float*)d_in[14];
    const float* lin_b    = (const float*)d_in[15];
    const float* out_w    = (const float*)d_in[16];
    const float* out_b    = (const float*)d_in[17];

    float* ws  = (float*)d_ws;
    float* out = (float*)d_out;

    unsigned short* seqs  = (unsigned short*)(ws + OFF_SEQS);
    unsigned short* h     = (unsigned short*)(ws + OFF_H);
    unsigned short* Bp    = (unsigned short*)(ws + OFF_BP);
    float* biasv          = ws + OFF_BIAS;
    unsigned short* wd    = (unsigned short*)(ws + OFF_WD);
    unsigned short* genew = (unsigned short*)(ws + OFF_GENEW);
    unsigned short* linw  = (unsigned short*)(ws + OFF_LINW);
    float* gene           = ws + OFF_GENE;
    float* stats          = ws + OFF_STATS;
    float* attn           = ws + OFF_ATTN;
    float* hid            = ws + OFF_HID;
    float* gpart          = ws + OFF_SEQS;  // alias: seqs dead after LSTM GEMM
    float* lpart          = ws + OFF_SEQS;  // alias: gpart dead after gene_reduce

    // 1. weight preps (bf16)
    prep_lstm_kernel<<<1600, 256, 0, stream>>>(w_ih_f, b_ih_f, b_hh_f,
                                               w_ih_b, b_ih_b, b_hh_b, Bp, biasv);
    prep_convw_kernel<<<160, 256, 0, stream>>>(conv_w, wd);
    prep_genew_kernel<<<24800, 256, 0, stream>>>(gene_w, genew);
    prep_linw_kernel<<<52032, 256, 0, stream>>>(lin_w, linw);
    // 2. fused conv -> seqs (pre-split hi|lo)
    conv_mfma_kernel<<<dim3(BB * 5, 3, 1), 256, 0, stream>>>(x, wd, conv_b, seqs);
    // 3. LSTM GEMM (XCD-pinned bm, bn-fastest) -> h bf16
    gemm2<0><<<dim3(8, 360), 256, 0, stream>>>(
        seqs, nullptr, 0, Bp, LSTM_K, nullptr,
        LSTM_M, LSTM_N, LSTM_K, 5, 5, nullptr, biasv, h);
    // 4. gene GEMM (split-K 16, XCD-pinned sp)
    gemm2<1><<<dim3(8, 42), 256, 0, stream>>>(
        nullptr, geneexpr, GENE_K, genew, GENE_KP, nullptr,
        BB, GENE_N, GENE_K, 310, 20, gpart, nullptr, nullptr);
    // 5. reduce + bias
    gene_reduce_kernel<<<1000, 256, 0, stream>>>(gpart, gene_b, gene);
    // 6-7. BN
    bn_stats_kernel<<<GENE_N, 256, 0, stream>>>(gene, stats);
    bn_apply_kernel<<<1000, 256, 0, stream>>>(gene, stats, bn_gamma, bn_beta);
    // 8. attention scores
    attn_kernel<<<LSTM_M, 64, 0, stream>>>(h, gene, attn);
    // 9. lin GEMM (split-K 8 = XCD, A = attn*h on the fly)
    gemm2<2><<<dim3(8, 56), 256, 0, stream>>>(
        h, nullptr, 0, linw, LIN_K, attn,
        BB, LIN_N, LIN_K, 225, 29, lpart, nullptr, nullptr);
    // 10. reduce + bias + relu
    lin_reduce_kernel<<<2891, 256, 0, stream>>>(lpart, lin_b, hid);
    // 11. final dot
    out_kernel<<<BB, 64, 0, stream>>>(hid, out_w, out_b, out);
}

// Round 8
// 484.923 us; speedup vs baseline: 7.6719x; 1.1407x over previous
//
#include <hip/hip_runtime.h>
#include <hip/hip_bf16.h>
#include <math.h>

// Problem constants
#define BB   800
#define CIN  4
#define XLEN 600
#define COUT 320
#define KW   26
#define TT   45
#define HID  160
#define LSTM_N 1280          // 2 dirs * [jg(10) x gate(4) x jl(16)] permuted
#define LSTM_K 320
#define LSTM_M 36000
#define GENE_K 19795
#define GENE_KP 19840        // padded to 64
#define GENE_N 320
#define LIN_K 14400
#define LIN_N 925
#define GENE_SPLITS 16
#define LIN_SPLITS 8

// Workspace layout (float units)
#define OFF_SEQS   ((size_t)0)          // [36000][640] ush (hi|lo) ; later gpart/lpart alias
#define OFF_H      ((size_t)11520000)   // [36000][320] ush bf16
#define OFF_BP     ((size_t)17280000)   // [1280][320] ush bf16 (permuted LSTM w)
#define OFF_BIAS   ((size_t)17484800)   // [1280] f32
#define OFF_WD     ((size_t)17486080)   // [320][128] ush (conv w bf16, k-padded)
#define OFF_GENEW  ((size_t)17506560)   // [320][19840] ush bf16
#define OFF_LINW   ((size_t)20680960)   // [925][14400] ush bf16
#define OFF_GENE   ((size_t)27340960)   // [800][320] f32
#define OFF_STATS  ((size_t)27596960)   // [640]
#define OFF_ATTN   ((size_t)27597600)   // [45*800]
#define OFF_HID    ((size_t)27633600)   // [800][925]

typedef __attribute__((ext_vector_type(8))) short short8v;
typedef __attribute__((ext_vector_type(8))) unsigned short ushort8v;
typedef __attribute__((ext_vector_type(4))) float f32x4;

__device__ __forceinline__ float sigf(float x) { return 1.0f / (1.0f + expf(-x)); }

__device__ __forceinline__ unsigned short bf16rne(float f) {
    unsigned u = __float_as_uint(f);
    return (unsigned short)((u + 0x7fffu + ((u >> 16) & 1u)) >> 16);
}
__device__ __forceinline__ float bf2f(unsigned short u) {
    return __uint_as_float((unsigned)u << 16);
}
// Truncation-based hi/lo split: f = hi + lo + O(2^-16 |f|)
__device__ __forceinline__ void split3(float f, unsigned& hi, unsigned& lo) {
    unsigned u = __float_as_uint(f);
    unsigned hu = u & 0xffff0000u;
    float d = f - __uint_as_float(hu);
    hi = u >> 16;
    lo = __float_as_uint(d) >> 16;
}

// ---------------------------------------------------------------------------
// Prep kernels: weights -> plain bf16 (RNE)
// ---------------------------------------------------------------------------
__global__ void prep_lstm_kernel(const float* __restrict__ wf, const float* __restrict__ bif,
                                 const float* __restrict__ bhf,
                                 const float* __restrict__ wb, const float* __restrict__ bib,
                                 const float* __restrict__ bhb,
                                 unsigned short* __restrict__ Bp, float* __restrict__ biasv) {
    int idx = blockIdx.x * 256 + threadIdx.x;
    if (idx < LSTM_N * LSTM_K) {
        int n = idx / LSTM_K, k = idx % LSTM_K;
        int dir = n / 640, r = n % 640;
        int jg = r >> 6, rr = r & 63, gate = rr >> 4, jl = rr & 15;
        int srow = gate * HID + jg * 16 + jl;
        const float* w = dir ? wb : wf;
        Bp[idx] = bf16rne(w[(size_t)srow * LSTM_K + k]);
    }
    if (idx < LSTM_N) {
        int n = idx;
        int dir = n / 640, r = n % 640;
        int jg = r >> 6, rr = r & 63, gate = rr >> 4, jl = rr & 15;
        int srow = gate * HID + jg * 16 + jl;
        biasv[n] = dir ? (bib[srow] + bhb[srow]) : (bif[srow] + bhf[srow]);
    }
}

__global__ void prep_convw_kernel(const float* __restrict__ cw, unsigned short* __restrict__ wd) {
    int idx = blockIdx.x * 256 + threadIdx.x;
    if (idx < COUT * 128) {
        int c = idx >> 7, k = idx & 127;
        wd[idx] = (k < 104) ? bf16rne(cw[(size_t)c * 104 + k]) : (unsigned short)0;
    }
}

__global__ void prep_genew_kernel(const float* __restrict__ gw, unsigned short* __restrict__ o) {
    int idx = blockIdx.x * 256 + threadIdx.x;
    if (idx < GENE_N * GENE_KP) {
        int c = idx / GENE_KP, k = idx % GENE_KP;
        o[idx] = (k < GENE_K) ? bf16rne(gw[(size_t)c * GENE_K + k]) : (unsigned short)0;
    }
}

__global__ void prep_linw_kernel(const float* __restrict__ lw, unsigned short* __restrict__ o) {
    int idx = blockIdx.x * 256 + threadIdx.x;
    if (idx < LIN_N * LIN_K) o[idx] = bf16rne(lw[idx]);
}

// ---------------------------------------------------------------------------
// Fused Conv1d + bias + ReLU + pad + MaxPool via MFMA.
// LDS 36 KB -> 4 blocks/CU: no B tile (B frags ping-pong prefetched from
// global/L2 into regs); C-scratch = half-tile [64][130] f32 aliasing As,
// pooled in two phases (window u=4 crosses the halves by one row).
// ---------------------------------------------------------------------------
#define AST 136
#define CST 130

__global__ __launch_bounds__(256, 4) void conv_mfma_kernel(const float* __restrict__ x,
                                                           const unsigned short* __restrict__ wd,
                                                           const float* __restrict__ cb,
                                                           unsigned short* __restrict__ seqs) {
    __shared__ __align__(16) unsigned char smem[36096];
    unsigned short* As = (unsigned short*)smem;              // [128][AST]
    unsigned short* xraw = As + 128 * AST;                   // [4][160]
    float* Csh = (float*)smem;                               // [64][CST], aliases As

    int bx = blockIdx.x;
    int b = bx / 5, wt = bx % 5;
    int col0 = blockIdx.y * 128;
    int p0 = 117 * wt - 14;
    int tid = threadIdx.x;

    const int w = tid >> 6, lane = tid & 63;
    const int wr = w >> 1, wc = w & 1;
    const int l15 = lane & 15, lq = lane >> 4;

    // B fragments from global (wd is 80KB, L2-hot). Row clamped for tail tile.
    ushort8v bA[4], bB[4];
#pragma unroll
    for (int n = 0; n < 4; ++n) {
        int cg = col0 + wc * 64 + n * 16 + l15;
        cg = min(cg, COUT - 1);
        bA[n] = *reinterpret_cast<const ushort8v*>(wd + (size_t)cg * 128 + 0 * 32 + lq * 8);
    }

    // 1. stage raw x window (bf16 RNE): positions p0 .. p0+153
    {
        const float* xb = x + (size_t)b * (CIN * XLEN);
        for (int j = tid; j < 4 * 160; j += 256) {
            int ch = j / 160, i = j - ch * 160;
            int p = p0 + i;
            float v = (i < 154 && p >= 0 && p < XLEN) ? xb[ch * XLEN + p] : 0.0f;
            xraw[ch * 160 + i] = bf16rne(v);
        }
    }
    __syncthreads();

    // 2. build im2col rows of A from xraw (LDS->LDS)
#pragma unroll
    for (int i = 0; i < 8; ++i) {
        int j = i * 256 + tid;
        int r = j >> 4, kg = j & 15;
        ushort8v o = {0, 0, 0, 0, 0, 0, 0, 0};
        if (kg < 13) {
#pragma unroll
            for (int e = 0; e < 8; ++e) {
                int k = kg * 8 + e;
                int ch = (k * 631) >> 14;
                int kk = k - ch * 26;
                o[e] = xraw[ch * 160 + r + kk];
            }
        }
        *reinterpret_cast<ushort8v*>(As + r * AST + kg * 8) = o;
    }
    __syncthreads();

    // 3. MFMA: 4 k-steps, B ping-pong prefetch from global
    f32x4 acc[4][4];
#pragma unroll
    for (int m = 0; m < 4; ++m)
#pragma unroll
        for (int n = 0; n < 4; ++n) acc[m][n] = (f32x4){0.f, 0.f, 0.f, 0.f};

#pragma unroll
    for (int ks = 0; ks < 4; ++ks) {
        const ushort8v* bcur = (ks & 1) ? bB : bA;
        ushort8v* bnext = (ks & 1) ? bA : bB;
        if (ks < 3) {
#pragma unroll
            for (int n = 0; n < 4; ++n) {
                int cg = col0 + wc * 64 + n * 16 + l15;
                cg = min(cg, COUT - 1);
                bnext[n] = *reinterpret_cast<const ushort8v*>(
                    wd + (size_t)cg * 128 + (ks + 1) * 32 + lq * 8);
            }
        }
        short8v af[4];
#pragma unroll
        for (int m = 0; m < 4; ++m)
            af[m] = *reinterpret_cast<const short8v*>(As + (wr * 64 + m * 16 + l15) * AST + ks * 32 + lq * 8);
#pragma unroll
        for (int m = 0; m < 4; ++m)
#pragma unroll
            for (int n = 0; n < 4; ++n)
                acc[m][n] = __builtin_amdgcn_mfma_f32_16x16x32_bf16(
                    af[m], *reinterpret_cast<const short8v*>(&bcur[n]), acc[m][n], 0, 0, 0);
    }
    __syncthreads();   // As dead; Csh aliases it

    const int rlo = (p0 < 0) ? -p0 : 0;    // rows < rlo are left-pad
    const int rhi = 575 - p0;              // rows >= rhi beyond conv output
    float pu4 = -1.0e30f;                  // partial max for window u=4 (tid<128)

    // 4a. wr=0 waves write C rows 0..63
    if (wr == 0) {
#pragma unroll
        for (int m = 0; m < 4; ++m)
#pragma unroll
            for (int n = 0; n < 4; ++n)
#pragma unroll
                for (int rg = 0; rg < 4; ++rg) {
                    int row = m * 16 + lq * 4 + rg;
                    int col = wc * 64 + n * 16 + l15;
                    Csh[row * CST + col] = acc[m][n][rg];
                }
    }
    __syncthreads();

    // 4b. pool windows u=0..3 (rows 0..51) + partial u=4 (rows 52..63)
#pragma unroll
    for (int i = 0; i < 2; ++i) {
        int j = i * 256 + tid;
        int u = j >> 7, c = j & 127;
        int cg = col0 + c;
        float mx = -1.0e30f;
#pragma unroll
        for (int jj = 0; jj < 13; ++jj) {
            int r = 13 * u + jj;
            if (r >= rlo && r < rhi) mx = fmaxf(mx, Csh[r * CST + c]);
        }
        if (cg < COUT) {
            float v = fmaxf(mx + cb[cg], 0.0f);
            unsigned hi, lo;
            split3(v, hi, lo);
            size_t rowi = (size_t)(wt * 9 + u) * BB + b;
            seqs[rowi * 640 + cg] = (unsigned short)hi;
            seqs[rowi * 640 + 320 + cg] = (unsigned short)lo;
        }
    }
    if (tid < 128) {
        int c = tid;
#pragma unroll
        for (int jj = 0; jj < 12; ++jj) {
            int r = 52 + jj;
            if (r >= rlo && r < rhi) pu4 = fmaxf(pu4, Csh[r * CST + c]);
        }
    }
    __syncthreads();

    // 5a. wr=1 waves write C rows 64..127 into the same half-buffer
    if (wr == 1) {
#pragma unroll
        for (int m = 0; m < 4; ++m)
#pragma unroll
            for (int n = 0; n < 4; ++n)
#pragma unroll
                for (int rg = 0; rg < 4; ++rg) {
                    int row = m * 16 + lq * 4 + rg;   // local = global-64
                    int col = wc * 64 + n * 16 + l15;
                    Csh[row * CST + col] = acc[m][n][rg];
                }
    }
    __syncthreads();

    // 5b. pool windows u=5..8 (rows 65..116 -> local 1..52) + finish u=4 (row 64)
#pragma unroll
    for (int i = 0; i < 2; ++i) {
        int j = i * 256 + tid;
        int u = 5 + (j >> 7), c = j & 127;
        int cg = col0 + c;
        float mx = -1.0e30f;
#pragma unroll
        for (int jj = 0; jj < 13; ++jj) {
            int r = 13 * u + jj;            // global row
            if (r >= rlo && r < rhi) mx = fmaxf(mx, Csh[(r - 64) * CST + c]);
        }
        if (cg < COUT) {
            float v = fmaxf(mx + cb[cg], 0.0f);
            unsigned hi, lo;
            split3(v, hi, lo);
            size_t rowi = (size_t)(wt * 9 + u) * BB + b;
            seqs[rowi * 640 + cg] = (unsigned short)hi;
            seqs[rowi * 640 + 320 + cg] = (unsigned short)lo;
        }
    }
    if (tid < 128) {
        int c = tid;
        int cg = col0 + c;
        if (64 >= rlo && 64 < rhi) pu4 = fmaxf(pu4, Csh[0 * CST + c]);
        if (cg < COUT) {
            float v = fmaxf(pu4 + cb[cg], 0.0f);
            unsigned hi, lo;
            split3(v, hi, lo);
            size_t rowi = (size_t)(wt * 9 + 4) * BB + b;
            seqs[rowi * 640 + cg] = (unsigned short)hi;
            seqs[rowi * 640 + 320 + cg] = (unsigned short)lo;
        }
    }
}

// ---------------------------------------------------------------------------
// gemm2: two-pass doubled GEMM. out[r][n] = sum_k A[r][k] * bf16(B[n][k]).
// A staged as [hi 64 | lo 64] ush per 64-k chunk; B plain bf16 [N][Kpad].
// VAR 0 = LSTM (A pre-split [M][640], epilogue -> h bf16, XCD grid)
// VAR 1 = gene (A f32 scalar-masked loads, split on the fly, split-K 16)
// VAR 2 = lin  (A = attn[t,r] * h_bf16, split on the fly, split-K 8)
// ---------------------------------------------------------------------------
template <int VAR>
__global__ __launch_bounds__(256) void gemm2(const unsigned short* __restrict__ Apre,
                                             const float* __restrict__ Af32, int lda,
                                             const unsigned short* __restrict__ Bn, int ldb,
                                             const float* __restrict__ attnp,
                                             int M, int N, int Kreal,
                                             int totChunks, int cps,
                                             float* __restrict__ outp,
                                             const float* __restrict__ biasv,
                                             unsigned short* __restrict__ hout) {
    __shared__ unsigned short Al[128][136];
    __shared__ unsigned short Bl[128][72];
    const int tid = threadIdx.x;

    int bm, bn, sp;
    if (VAR == 0) {
        int xcd = blockIdx.x;
        bn = blockIdx.y % 10;
        bm = xcd + 8 * (blockIdx.y / 10);
        sp = 0;
        if (bm >= 282) return;
    } else if (VAR == 1) {
        int xcd = blockIdx.x;
        sp = xcd + 8 * (blockIdx.y / 21);
        int r = blockIdx.y % 21;
        bm = r / 3; bn = r % 3;
    } else {
        sp = blockIdx.x;
        bn = blockIdx.y / 7; bm = blockIdx.y % 7;
    }
    const int row0 = bm * 128, col0 = bn * 128;
    const int c_beg = sp * cps;
    const int c_end = min(totChunks, c_beg + cps);

    const int w = tid >> 6, lane = tid & 63;
    const int wr = w >> 1, wc = w & 1;
    const int l15 = lane & 15, lq = lane >> 4;

    f32x4 acc[4][4];
#pragma unroll
    for (int m = 0; m < 4; ++m)
#pragma unroll
        for (int n = 0; n < 4; ++n) acc[m][n] = (f32x4){0.f, 0.f, 0.f, 0.f};

    ushort8v aP[8];      // VAR0 raw, VAR2 raw h
    float4 aF[8];        // VAR1 raw f32
    float aW[4];         // VAR2 attn weights
    ushort8v bP[4];

    auto loadA = [&](int c) {
        int k0 = c * 64;
        if (VAR == 0) {
#pragma unroll
            for (int i = 0; i < 8; ++i) {
                int j = tid + i * 256;
                int r = j >> 4, cg = j & 15;
                int gr = row0 + r;
                ushort8v z = {0, 0, 0, 0, 0, 0, 0, 0};
                if (gr < M) {
                    int colu = (cg < 8) ? (k0 + cg * 8) : (320 + k0 + (cg - 8) * 8);
                    z = *reinterpret_cast<const ushort8v*>(Apre + (size_t)gr * 640 + colu);
                }
                aP[i] = z;
            }
        } else if (VAR == 1) {
#pragma unroll
            for (int i = 0; i < 4; ++i) {
                int j = tid + i * 256;
                int r = j >> 3, kg = j & 7;
                int gr = row0 + r;
                float4 v0 = make_float4(0.f, 0.f, 0.f, 0.f);
                float4 v1 = make_float4(0.f, 0.f, 0.f, 0.f);
                if (gr < M) {
                    int kb = k0 + kg * 8;
                    const float* p = Af32 + (size_t)gr * lda + kb;
                    if (kb + 0 < Kreal) v0.x = p[0];
                    if (kb + 1 < Kreal) v0.y = p[1];
                    if (kb + 2 < Kreal) v0.z = p[2];
                    if (kb + 3 < Kreal) v0.w = p[3];
                    if (kb + 4 < Kreal) v1.x = p[4];
                    if (kb + 5 < Kreal) v1.y = p[5];
                    if (kb + 6 < Kreal) v1.z = p[6];
                    if (kb + 7 < Kreal) v1.w = p[7];
                }
                aF[2 * i] = v0; aF[2 * i + 1] = v1;
            }
        } else {
            int t = k0 / 320, d0 = k0 - t * 320;
#pragma unroll
            for (int i = 0; i < 4; ++i) {
                int j = tid + i * 256;
                int r = j >> 3, kg = j & 7;
                int gr = row0 + r;
                ushort8v z = {0, 0, 0, 0, 0, 0, 0, 0};
                float aw = 0.0f;
                if (gr < M) {
                    z = *reinterpret_cast<const ushort8v*>(
                        Apre + ((size_t)t * BB + gr) * 320 + d0 + kg * 8);
                    aw = attnp[t * BB + gr];
                }
                aP[i] = z; aW[i] = aw;
            }
        }
    };
    auto loadB = [&](int c) {
        int k0 = c * 64;
#pragma unroll
        for (int i = 0; i < 4; ++i) {
            int j = tid + i * 256;
            int r = j >> 3, sg = j & 7;
            int gc = col0 + r;
            ushort8v z = {0, 0, 0, 0, 0, 0, 0, 0};
            if (gc < N) z = *reinterpret_cast<const ushort8v*>(Bn + (size_t)gc * ldb + k0 + sg * 8);
            bP[i] = z;
        }
    };
    auto writeAB = [&]() {
        if (VAR == 0) {
#pragma unroll
            for (int i = 0; i < 8; ++i) {
                int j = tid + i * 256;
                int r = j >> 4, cg = j & 15;
                *reinterpret_cast<ushort8v*>(&Al[r][cg * 8]) = aP[i];
            }
        } else {
#pragma unroll
            for (int i = 0; i < 4; ++i) {
                int j = tid + i * 256;
                int r = j >> 3, kg = j & 7;
                float f[8];
                if (VAR == 1) {
                    f[0] = aF[2 * i].x; f[1] = aF[2 * i].y; f[2] = aF[2 * i].z; f[3] = aF[2 * i].w;
                    f[4] = aF[2 * i + 1].x; f[5] = aF[2 * i + 1].y; f[6] = aF[2 * i + 1].z; f[7] = aF[2 * i + 1].w;
                } else {
#pragma unroll
                    for (int e = 0; e < 8; ++e) f[e] = bf2f(aP[i][e]) * aW[i];
                }
                ushort8v hv, lv;
#pragma unroll
                for (int e = 0; e < 8; ++e) {
                    unsigned hh, ll;
                    split3(f[e], hh, ll);
                    hv[e] = (unsigned short)hh; lv[e] = (unsigned short)ll;
                }
                *reinterpret_cast<ushort8v*>(&Al[r][kg * 8]) = hv;
                *reinterpret_cast<ushort8v*>(&Al[r][64 + kg * 8]) = lv;
            }
        }
#pragma unroll
        for (int i = 0; i < 4; ++i) {
            int j = tid + i * 256;
            int r = j >> 3, sg = j & 7;
            *reinterpret_cast<ushort8v*>(&Bl[r][sg * 8]) = bP[i];
        }
    };

    loadA(c_beg); loadB(c_beg);

    for (int c = c_beg; c < c_end; ++c) {
        __syncthreads();
        writeAB();
        __syncthreads();
        if (c + 1 < c_end) { loadA(c + 1); loadB(c + 1); }

#pragma unroll
        for (int ks = 0; ks < 2; ++ks) {
            short8v bf[4];
#pragma unroll
            for (int n = 0; n < 4; ++n)
                bf[n] = *reinterpret_cast<const short8v*>(&Bl[wc * 64 + n * 16 + l15][ks * 32 + lq * 8]);
#pragma unroll
            for (int pass = 0; pass < 2; ++pass) {
                short8v af[4];
#pragma unroll
                for (int m = 0; m < 4; ++m)
                    af[m] = *reinterpret_cast<const short8v*>(
                        &Al[wr * 64 + m * 16 + l15][pass * 64 + ks * 32 + lq * 8]);
#pragma unroll
                for (int m = 0; m < 4; ++m)
#pragma unroll
                    for (int n = 0; n < 4; ++n)
                        acc[m][n] = __builtin_amdgcn_mfma_f32_16x16x32_bf16(af[m], bf[n], acc[m][n], 0, 0, 0);
            }
        }
    }

    if (VAR != 0) {
#pragma unroll
        for (int m = 0; m < 4; ++m)
#pragma unroll
            for (int n = 0; n < 4; ++n)
#pragma unroll
                for (int rg = 0; rg < 4; ++rg) {
                    int row_g = row0 + wr * 64 + m * 16 + lq * 4 + rg;
                    int col_g = col0 + wc * 64 + n * 16 + l15;
                    if (row_g < M && col_g < N)
                        outp[((size_t)sp * M + row_g) * N + col_g] = acc[m][n][rg];
                }
    } else {
        int c0 = col0 + wc * 64;
        int dir = c0 / 640;
        int jgl = (c0 % 640) >> 6;
        int hcol = dir * HID + jgl * 16 + l15;
        float bi = biasv[c0 + l15];
        float bg = biasv[c0 + 32 + l15];
        float bo = biasv[c0 + 48 + l15];
#pragma unroll
        for (int m = 0; m < 4; ++m)
#pragma unroll
            for (int rg = 0; rg < 4; ++rg) {
                int row_g = row0 + wr * 64 + m * 16 + lq * 4 + rg;
                if (row_g >= M) continue;
                float gi = acc[m][0][rg] + bi;
                float gg = acc[m][2][rg] + bg;
                float go = acc[m][3][rg] + bo;
                float cc = sigf(gi) * tanhf(gg);
                hout[(size_t)row_g * 320 + hcol] = bf16rne(sigf(go) * tanhf(cc));
            }
    }
}

// ---------------------------------------------------------------------------
__global__ void gene_reduce_kernel(const float* __restrict__ part, const float* __restrict__ gene_b,
                                   float* __restrict__ out) {
    int idx = blockIdx.x * 256 + threadIdx.x;
    if (idx >= BB * GENE_N) return;
    int n = idx % GENE_N;
    float sum = gene_b[n];
#pragma unroll
    for (int ss = 0; ss < GENE_SPLITS; ++ss) sum += part[(size_t)ss * (BB * GENE_N) + idx];
    out[idx] = sum;
}

__global__ void bn_stats_kernel(const float* __restrict__ g, float* __restrict__ stats) {
    int n = blockIdx.x;
    int tid = threadIdx.x;
    float s = 0.0f, s2 = 0.0f;
    for (int m = tid; m < BB; m += 256) {
        float v = g[(size_t)m * GENE_N + n];
        s += v; s2 += v * v;
    }
    __shared__ float red0[256], red1[256];
    red0[tid] = s; red1[tid] = s2;
    __syncthreads();
    for (int off = 128; off; off >>= 1) {
        if (tid < off) { red0[tid] += red0[tid + off]; red1[tid] += red1[tid + off]; }
        __syncthreads();
    }
    if (tid == 0) {
        float mean = red0[0] / (float)BB;
        float var = red1[0] / (float)BB - mean * mean;
        stats[n] = mean;
        stats[GENE_N + n] = rsqrtf(var + 1e-5f);
    }
}

__global__ void bn_apply_kernel(float* __restrict__ g, const float* __restrict__ stats,
                                const float* __restrict__ gamma, const float* __restrict__ beta) {
    int idx = blockIdx.x * 256 + threadIdx.x;
    if (idx >= BB * GENE_N) return;
    int n = idx % GENE_N;
    float v = (g[idx] - stats[n]) * stats[GENE_N + n] * gamma[n] + beta[n];
    g[idx] = fmaxf(v, 0.0f);
}

__global__ void attn_kernel(const unsigned short* __restrict__ h, const float* __restrict__ gene,
                            float* __restrict__ attn) {
    int r = blockIdx.x;
    int b = r % BB;
    int lane = threadIdx.x;
    const unsigned short* hr = h + (size_t)r * 320;
    const float* gr = gene + (size_t)b * 320;
    float s = 0.0f;
    for (int d = lane; d < 320; d += 64) s += bf2f(hr[d]) * gr[d];
    for (int off = 32; off; off >>= 1) s += __shfl_down(s, off);
    if (lane == 0) attn[r] = s;
}

__global__ void lin_reduce_kernel(const float* __restrict__ part, const float* __restrict__ lin_b,
                                  float* __restrict__ hid) {
    int idx = blockIdx.x * 256 + threadIdx.x;
    if (idx >= BB * LIN_N) return;
    int n = idx % LIN_N;
    float sum = lin_b[n];
#pragma unroll
    for (int ss = 0; ss < LIN_SPLITS; ++ss) sum += part[(size_t)ss * (BB * LIN_N) + idx];
    hid[idx] = fmaxf(sum, 0.0f);
}

__global__ void out_kernel(const float* __restrict__ hid, const float* __restrict__ ow,
                           const float* __restrict__ ob, float* __restrict__ out) {
    int b = blockIdx.x;
    int lane = threadIdx.x;
    float s = 0.0f;
    for (int n = lane; n < LIN_N; n += 64) s += hid[(size_t)b * LIN_N + n] * ow[n];
    for (int off = 32; off; off >>= 1) s += __shfl_down(s, off);
    if (lane == 0) out[b] = s + ob[0];
}

// ---------------------------------------------------------------------------
extern "C" void kernel_launch(void* const* d_in, const int* in_sizes, int n_in,
                              void* d_out, int out_size, void* d_ws, size_t ws_size,
                              hipStream_t stream) {
    const float* x        = (const float*)d_in[0];
    const float* geneexpr = (const float*)d_in[1];
    const float* conv_w   = (const float*)d_in[2];
    const float* conv_b   = (const float*)d_in[3];
    const float* w_ih_f   = (const float*)d_in[4];
    const float* b_ih_f   = (const float*)d_in[5];
    const float* b_hh_f   = (const float*)d_in[6];
    const float* w_ih_b   = (const float*)d_in[7];
    const float* b_ih_b   = (const float*)d_in[8];
    const float* b_hh_b   = (const float*)d_in[9];
    const float* gene_w   = (const float*)d_in[10];
    const float* gene_b   = (const float*)d_in[11];
    const float* bn_gamma = (const float*)d_in[12];
    const float* bn_beta  = (const float*)d_in[13];
    const float* lin_w    = (const float*)d_in[14];
    const float* lin_b    = (const float*)d_in[15];
    const float* out_w    = (const float*)d_in[16];
    const float* out_b    = (const float*)d_in[17];

    float* ws  = (float*)d_ws;
    float* out = (float*)d_out;

    unsigned short* seqs  = (unsigned short*)(ws + OFF_SEQS);
    unsigned short* h     = (unsigned short*)(ws + OFF_H);
    unsigned short* Bp    = (unsigned short*)(ws + OFF_BP);
    float* biasv          = ws + OFF_BIAS;
    unsigned short* wd    = (unsigned short*)(ws + OFF_WD);
    unsigned short* genew = (unsigned short*)(ws + OFF_GENEW);
    unsigned short* linw  = (unsigned short*)(ws + OFF_LINW);
    float* gene           = ws + OFF_GENE;
    float* stats          = ws + OFF_STATS;
    float* attn           = ws + OFF_ATTN;
    float* hid            = ws + OFF_HID;
    float* gpart          = ws + OFF_SEQS;  // alias: seqs dead after LSTM GEMM
    float* lpart          = ws + OFF_SEQS;  // alias: gpart dead after gene_reduce

    // 1. weight preps (bf16)
    prep_lstm_kernel<<<1600, 256, 0, stream>>>(w_ih_f, b_ih_f, b_hh_f,
                                               w_ih_b, b_ih_b, b_hh_b, Bp, biasv);
    prep_convw_kernel<<<160, 256, 0, stream>>>(conv_w, wd);
    prep_genew_kernel<<<24800, 256, 0, stream>>>(gene_w, genew);
    prep_linw_kernel<<<52032, 256, 0, stream>>>(lin_w, linw);
    // 2. fused conv -> seqs (pre-split hi|lo)
    conv_mfma_kernel<<<dim3(BB * 5, 3, 1), 256, 0, stream>>>(x, wd, conv_b, seqs);
    // 3. LSTM GEMM (XCD-pinned bm, bn-fastest) -> h bf16
    gemm2<0><<<dim3(8, 360), 256, 0, stream>>>(
        seqs, nullptr, 0, Bp, LSTM_K, nullptr,
        LSTM_M, LSTM_N, LSTM_K, 5, 5, nullptr, biasv, h);
    // 4. gene GEMM (split-K 16, XCD-pinned sp)
    gemm2<1><<<dim3(8, 42), 256, 0, stream>>>(
        nullptr, geneexpr, GENE_K, genew, GENE_KP, nullptr,
        BB, GENE_N, GENE_K, 310, 20, gpart, nullptr, nullptr);
    // 5. reduce + bias
    gene_reduce_kernel<<<1000, 256, 0, stream>>>(gpart, gene_b, gene);
    // 6-7. BN
    bn_stats_kernel<<<GENE_N, 256, 0, stream>>>(gene, stats);
    bn_apply_kernel<<<1000, 256, 0, stream>>>(gene, stats, bn_gamma, bn_beta);
    // 8. attention scores
    attn_kernel<<<LSTM_M, 64, 0, stream>>>(h, gene, attn);
    // 9. lin GEMM (split-K 8 = XCD, A = attn*h on the fly)
    gemm2<2><<<dim3(8, 56), 256, 0, stream>>>(
        h, nullptr, 0, linw, LIN_K, attn,
        BB, LIN_N, LIN_K, 225, 29, lpart, nullptr, nullptr);
    // 10. reduce + bias + relu
    lin_reduce_kernel<<<2891, 256, 0, stream>>>(lpart, lin_b, hid);
    // 11. final dot
    out_kernel<<<BB, 64, 0, stream>>>(hid, out_w, out_b, out);
}

// Round 9
// 420.888 us; speedup vs baseline: 8.8391x; 1.1521x over previous
//
#include <hip/hip_runtime.h>
#include <hip/hip_bf16.h>
#include <math.h>

// Problem constants
#define BB   800
#define CIN  4
#define XLEN 600
#define COUT 320
#define KW   26
#define TT   45
#define HID  160
#define LSTM_N 1280          // 2 dirs * [jg(10) x gate(4) x jl(16)] permuted
#define LSTM_K 320
#define LSTM_M 36000
#define GENE_K 19795
#define GENE_KP 19840        // padded to 64
#define GENE_N 320
#define LIN_K 14400
#define LIN_N 925
#define GENE_SPLITS 16
#define LIN_SPLITS 8

// Workspace layout (float units)
#define OFF_SEQS   ((size_t)0)          // [36000][640] ush (hi|lo) ; later gpart/lpart alias
#define OFF_H      ((size_t)11520000)   // [36000][320] ush bf16
#define OFF_BP     ((size_t)17280000)   // [1280][320] ush bf16 (permuted LSTM w)
#define OFF_BIAS   ((size_t)17484800)   // [1280] f32
#define OFF_WD     ((size_t)17486080)   // [320][128] ush (conv w bf16, per-ch padded 26->32)
#define OFF_GENEW  ((size_t)17506560)   // [320][19840] ush bf16
#define OFF_LINW   ((size_t)20680960)   // [925][14400] ush bf16
#define OFF_GENE   ((size_t)27340960)   // [800][320] f32
#define OFF_STATS  ((size_t)27596960)   // [640]
#define OFF_ATTN   ((size_t)27597600)   // [45*800]
#define OFF_HID    ((size_t)27633600)   // [800][925]

typedef __attribute__((ext_vector_type(8))) short short8v;
typedef __attribute__((ext_vector_type(8))) unsigned short ushort8v;
typedef __attribute__((ext_vector_type(4))) float f32x4;

__device__ __forceinline__ float sigf(float x) { return 1.0f / (1.0f + expf(-x)); }

__device__ __forceinline__ unsigned short bf16rne(float f) {
    unsigned u = __float_as_uint(f);
    return (unsigned short)((u + 0x7fffu + ((u >> 16) & 1u)) >> 16);
}
__device__ __forceinline__ float bf2f(unsigned short u) {
    return __uint_as_float((unsigned)u << 16);
}
// Truncation-based hi/lo split: f = hi + lo + O(2^-16 |f|)
__device__ __forceinline__ void split3(float f, unsigned& hi, unsigned& lo) {
    unsigned u = __float_as_uint(f);
    unsigned hu = u & 0xffff0000u;
    float d = f - __uint_as_float(hu);
    hi = u >> 16;
    lo = __float_as_uint(d) >> 16;
}

// ---------------------------------------------------------------------------
// Prep kernels: weights -> plain bf16 (RNE)
// ---------------------------------------------------------------------------
__global__ void prep_lstm_kernel(const float* __restrict__ wf, const float* __restrict__ bif,
                                 const float* __restrict__ bhf,
                                 const float* __restrict__ wb, const float* __restrict__ bib,
                                 const float* __restrict__ bhb,
                                 unsigned short* __restrict__ Bp, float* __restrict__ biasv) {
    int idx = blockIdx.x * 256 + threadIdx.x;
    if (idx < LSTM_N * LSTM_K) {
        int n = idx / LSTM_K, k = idx % LSTM_K;
        int dir = n / 640, r = n % 640;
        int jg = r >> 6, rr = r & 63, gate = rr >> 4, jl = rr & 15;
        int srow = gate * HID + jg * 16 + jl;
        const float* w = dir ? wb : wf;
        Bp[idx] = bf16rne(w[(size_t)srow * LSTM_K + k]);
    }
    if (idx < LSTM_N) {
        int n = idx;
        int dir = n / 640, r = n % 640;
        int jg = r >> 6, rr = r & 63, gate = rr >> 4, jl = rr & 15;
        int srow = gate * HID + jg * 16 + jl;
        biasv[n] = dir ? (bib[srow] + bhb[srow]) : (bif[srow] + bhf[srow]);
    }
}

// Conv weights: per-channel padded layout k = ch*32 + kk (kk<26 valid, else 0)
__global__ void prep_convw_kernel(const float* __restrict__ cw, unsigned short* __restrict__ wd) {
    int idx = blockIdx.x * 256 + threadIdx.x;
    if (idx < COUT * 128) {
        int c = idx >> 7, k = idx & 127;
        int ch = k >> 5, kk = k & 31;
        wd[idx] = (kk < KW) ? bf16rne(cw[(size_t)c * 104 + ch * KW + kk]) : (unsigned short)0;
    }
}

__global__ void prep_genew_kernel(const float* __restrict__ gw, unsigned short* __restrict__ o) {
    int idx = blockIdx.x * 256 + threadIdx.x;
    if (idx < GENE_N * GENE_KP) {
        int c = idx / GENE_KP, k = idx % GENE_KP;
        o[idx] = (k < GENE_K) ? bf16rne(gw[(size_t)c * GENE_K + k]) : (unsigned short)0;
    }
}

__global__ void prep_linw_kernel(const float* __restrict__ lw, unsigned short* __restrict__ o) {
    int idx = blockIdx.x * 256 + threadIdx.x;
    if (idx < LIN_N * LIN_K) o[idx] = bf16rne(lw[idx]);
}

// ---------------------------------------------------------------------------
// Fused Conv1d + bias + ReLU + pad + MaxPool via MFMA.
// LDS 36 KB -> 4 blocks/CU. Channel-padded K layout: ch = kg>>2, kk base
// uniform per kgroup -> one LDS base + 8 offset reads (no per-elem arith).
// Masking wave-uniform: staging masked only wt in {0,4}; pool masked only
// wt==0 phase-4b (rhi never binds: pool rows <=116 < 121).
// ---------------------------------------------------------------------------
#define AST 136
#define CST 130

__global__ __launch_bounds__(256, 4) void conv_mfma_kernel(const float* __restrict__ x,
                                                           const unsigned short* __restrict__ wd,
                                                           const float* __restrict__ cb,
                                                           unsigned short* __restrict__ seqs) {
    __shared__ __align__(16) unsigned char smem[36096];
    unsigned short* As = (unsigned short*)smem;              // [128][AST]
    unsigned short* xraw = As + 128 * AST;                   // [4][160]
    float* Csh = (float*)smem;                               // [64][CST], aliases As

    int bx = blockIdx.x;
    int b = bx / 5, wt = bx % 5;
    int col0 = blockIdx.y * 128;
    int p0 = 117 * wt - 14;
    int tid = threadIdx.x;

    const int w = tid >> 6, lane = tid & 63;
    const int wr = w >> 1, wc = w & 1;
    const int l15 = lane & 15, lq = lane >> 4;

    // B fragments from global (wd is 80KB, L2-hot). Row clamped for tail tile.
    ushort8v bA[4], bB[4];
#pragma unroll
    for (int n = 0; n < 4; ++n) {
        int cg = col0 + wc * 64 + n * 16 + l15;
        cg = min(cg, COUT - 1);
        bA[n] = *reinterpret_cast<const ushort8v*>(wd + (size_t)cg * 128 + 0 * 32 + lq * 8);
    }

    // 1. stage raw x window (bf16 RNE): positions p0 .. p0+153; idx 154..159 = 0
    {
        const float* xb = x + (size_t)b * (CIN * XLEN);
        if (wt >= 1 && wt <= 3) {           // interior: no p-bounds checks
            for (int j = tid; j < 4 * 160; j += 256) {
                int ch = j / 160, i = j - ch * 160;
                float v = (i < 154) ? xb[ch * XLEN + p0 + i] : 0.0f;
                xraw[ch * 160 + i] = bf16rne(v);
            }
        } else {
            for (int j = tid; j < 4 * 160; j += 256) {
                int ch = j / 160, i = j - ch * 160;
                int p = p0 + i;
                float v = (i < 154 && p >= 0 && p < XLEN) ? xb[ch * XLEN + p] : 0.0f;
                xraw[ch * 160 + i] = bf16rne(v);
            }
        }
    }
    __syncthreads();

    // 2. build im2col rows of A from xraw (LDS->LDS); k = ch*32 + kk
#pragma unroll
    for (int i = 0; i < 8; ++i) {
        int j = i * 256 + tid;
        int r = j >> 4, kg = j & 15;
        int ch = kg >> 2, q = kg & 3;
        const unsigned short* src = xraw + ch * 160 + r + q * 8;
        ushort8v o;
        if (q < 3) {
#pragma unroll
            for (int e = 0; e < 8; ++e) o[e] = src[e];
        } else {                              // kk = 24..31: only 24,25 valid
            o = (ushort8v){src[0], src[1], 0, 0, 0, 0, 0, 0};
        }
        *reinterpret_cast<ushort8v*>(As + r * AST + kg * 8) = o;
    }
    __syncthreads();

    // 3. MFMA: 4 k-steps, B ping-pong prefetch from global
    f32x4 acc[4][4];
#pragma unroll
    for (int m = 0; m < 4; ++m)
#pragma unroll
        for (int n = 0; n < 4; ++n) acc[m][n] = (f32x4){0.f, 0.f, 0.f, 0.f};

#pragma unroll
    for (int ks = 0; ks < 4; ++ks) {
        const ushort8v* bcur = (ks & 1) ? bB : bA;
        ushort8v* bnext = (ks & 1) ? bA : bB;
        if (ks < 3) {
#pragma unroll
            for (int n = 0; n < 4; ++n) {
                int cg = col0 + wc * 64 + n * 16 + l15;
                cg = min(cg, COUT - 1);
                bnext[n] = *reinterpret_cast<const ushort8v*>(
                    wd + (size_t)cg * 128 + (ks + 1) * 32 + lq * 8);
            }
        }
        short8v af[4];
#pragma unroll
        for (int m = 0; m < 4; ++m)
            af[m] = *reinterpret_cast<const short8v*>(As + (wr * 64 + m * 16 + l15) * AST + ks * 32 + lq * 8);
#pragma unroll
        for (int m = 0; m < 4; ++m)
#pragma unroll
            for (int n = 0; n < 4; ++n)
                acc[m][n] = __builtin_amdgcn_mfma_f32_16x16x32_bf16(
                    af[m], *reinterpret_cast<const short8v*>(&bcur[n]), acc[m][n], 0, 0, 0);
    }
    __syncthreads();   // As dead; Csh aliases it

    float pu4 = -1.0e30f;                  // partial max for window u=4 (tid<128)

    // 4a. wr=0 waves write C rows 0..63
    if (wr == 0) {
#pragma unroll
        for (int m = 0; m < 4; ++m)
#pragma unroll
            for (int n = 0; n < 4; ++n)
#pragma unroll
                for (int rg = 0; rg < 4; ++rg) {
                    int row = m * 16 + lq * 4 + rg;
                    int col = wc * 64 + n * 16 + l15;
                    Csh[row * CST + col] = acc[m][n][rg];
                }
    }
    __syncthreads();

    // 4b. pool windows u=0..3 (rows 0..51) + partial u=4 (rows 52..63)
#pragma unroll
    for (int i = 0; i < 2; ++i) {
        int j = i * 256 + tid;
        int u = j >> 7, c = j & 127;
        int cg = col0 + c;
        float mx = -1.0e30f;
        if (wt == 0) {                       // left-pad: rows < 14 excluded
#pragma unroll
            for (int jj = 0; jj < 13; ++jj) {
                int r = 13 * u + jj;
                if (r >= 14) mx = fmaxf(mx, Csh[r * CST + c]);
            }
        } else {
#pragma unroll
            for (int jj = 0; jj < 13; ++jj) {
                int r = 13 * u + jj;
                mx = fmaxf(mx, Csh[r * CST + c]);
            }
        }
        if (cg < COUT) {
            float v = fmaxf(mx + cb[cg], 0.0f);
            unsigned hi, lo;
            split3(v, hi, lo);
            size_t rowi = (size_t)(wt * 9 + u) * BB + b;
            seqs[rowi * 640 + cg] = (unsigned short)hi;
            seqs[rowi * 640 + 320 + cg] = (unsigned short)lo;
        }
    }
    if (tid < 128) {                         // rows 52..63: never masked
        int c = tid;
#pragma unroll
        for (int jj = 0; jj < 12; ++jj) pu4 = fmaxf(pu4, Csh[(52 + jj) * CST + c]);
    }
    __syncthreads();

    // 5a. wr=1 waves write C rows 64..127 into the same half-buffer
    if (wr == 1) {
#pragma unroll
        for (int m = 0; m < 4; ++m)
#pragma unroll
            for (int n = 0; n < 4; ++n)
#pragma unroll
                for (int rg = 0; rg < 4; ++rg) {
                    int row = m * 16 + lq * 4 + rg;   // local = global-64
                    int col = wc * 64 + n * 16 + l15;
                    Csh[row * CST + col] = acc[m][n][rg];
                }
    }
    __syncthreads();

    // 5b. pool windows u=5..8 (rows 65..116, never masked) + finish u=4 (row 64)
#pragma unroll
    for (int i = 0; i < 2; ++i) {
        int j = i * 256 + tid;
        int u = 5 + (j >> 7), c = j & 127;
        int cg = col0 + c;
        float mx = -1.0e30f;
#pragma unroll
        for (int jj = 0; jj < 13; ++jj) {
            int r = 13 * u + jj;              // global row
            mx = fmaxf(mx, Csh[(r - 64) * CST + c]);
        }
        if (cg < COUT) {
            float v = fmaxf(mx + cb[cg], 0.0f);
            unsigned hi, lo;
            split3(v, hi, lo);
            size_t rowi = (size_t)(wt * 9 + u) * BB + b;
            seqs[rowi * 640 + cg] = (unsigned short)hi;
            seqs[rowi * 640 + 320 + cg] = (unsigned short)lo;
        }
    }
    if (tid < 128) {
        int c = tid;
        int cg = col0 + c;
        pu4 = fmaxf(pu4, Csh[0 * CST + c]);   // row 64
        if (cg < COUT) {
            float v = fmaxf(pu4 + cb[cg], 0.0f);
            unsigned hi, lo;
            split3(v, hi, lo);
            size_t rowi = (size_t)(wt * 9 + 4) * BB + b;
            seqs[rowi * 640 + cg] = (unsigned short)hi;
            seqs[rowi * 640 + 320 + cg] = (unsigned short)lo;
        }
    }
}

// ---------------------------------------------------------------------------
// gemm2: two-pass doubled GEMM. out[r][n] = sum_k A[r][k] * bf16(B[n][k]).
// A staged as [hi 64 | lo 64] ush per 64-k chunk; B plain bf16 [N][Kpad].
// VAR 0 = LSTM (A pre-split [M][640], epilogue -> h bf16, XCD grid)
// VAR 1 = gene (A f32 float4 fast path; masked only on last chunk)
// VAR 2 = lin  (A = attn[t,r] * h_bf16, split on the fly, split-K 8)
// ---------------------------------------------------------------------------
template <int VAR>
__global__ __launch_bounds__(256) void gemm2(const unsigned short* __restrict__ Apre,
                                             const float* __restrict__ Af32, int lda,
                                             const unsigned short* __restrict__ Bn, int ldb,
                                             const float* __restrict__ attnp,
                                             int M, int N, int Kreal,
                                             int totChunks, int cps,
                                             float* __restrict__ outp,
                                             const float* __restrict__ biasv,
                                             unsigned short* __restrict__ hout) {
    __shared__ unsigned short Al[128][136];
    __shared__ unsigned short Bl[128][72];
    const int tid = threadIdx.x;

    int bm, bn, sp;
    if (VAR == 0) {
        int xcd = blockIdx.x;
        bn = blockIdx.y % 10;
        bm = xcd + 8 * (blockIdx.y / 10);
        sp = 0;
        if (bm >= 282) return;
    } else if (VAR == 1) {
        int xcd = blockIdx.x;
        sp = xcd + 8 * (blockIdx.y / 21);
        int r = blockIdx.y % 21;
        bm = r / 3; bn = r % 3;
    } else {
        sp = blockIdx.x;
        bn = blockIdx.y / 7; bm = blockIdx.y % 7;
    }
    const int row0 = bm * 128, col0 = bn * 128;
    const int c_beg = sp * cps;
    const int c_end = min(totChunks, c_beg + cps);

    const int w = tid >> 6, lane = tid & 63;
    const int wr = w >> 1, wc = w & 1;
    const int l15 = lane & 15, lq = lane >> 4;

    f32x4 acc[4][4];
#pragma unroll
    for (int m = 0; m < 4; ++m)
#pragma unroll
        for (int n = 0; n < 4; ++n) acc[m][n] = (f32x4){0.f, 0.f, 0.f, 0.f};

    ushort8v aP[8];      // VAR0 raw, VAR2 raw h
    float4 aF[8];        // VAR1 raw f32
    float aW[4];         // VAR2 attn weights
    ushort8v bP[4];

    auto loadA = [&](int c) {
        int k0 = c * 64;
        if (VAR == 0) {
#pragma unroll
            for (int i = 0; i < 8; ++i) {
                int j = tid + i * 256;
                int r = j >> 4, cg = j & 15;
                int gr = row0 + r;
                ushort8v z = {0, 0, 0, 0, 0, 0, 0, 0};
                if (gr < M) {
                    int colu = (cg < 8) ? (k0 + cg * 8) : (320 + k0 + (cg - 8) * 8);
                    z = *reinterpret_cast<const ushort8v*>(Apre + (size_t)gr * 640 + colu);
                }
                aP[i] = z;
            }
        } else if (VAR == 1) {
            bool fast = (k0 + 64 <= Kreal);
#pragma unroll
            for (int i = 0; i < 4; ++i) {
                int j = tid + i * 256;
                int r = j >> 3, kg = j & 7;
                int gr = row0 + r;
                float4 v0 = make_float4(0.f, 0.f, 0.f, 0.f);
                float4 v1 = make_float4(0.f, 0.f, 0.f, 0.f);
                if (gr < M) {
                    int kb = k0 + kg * 8;
                    const float* p = Af32 + (size_t)gr * lda + kb;
                    if (fast) {
                        v0 = *reinterpret_cast<const float4*>(p);
                        v1 = *reinterpret_cast<const float4*>(p + 4);
                    } else {
                        if (kb + 0 < Kreal) v0.x = p[0];
                        if (kb + 1 < Kreal) v0.y = p[1];
                        if (kb + 2 < Kreal) v0.z = p[2];
                        if (kb + 3 < Kreal) v0.w = p[3];
                        if (kb + 4 < Kreal) v1.x = p[4];
                        if (kb + 5 < Kreal) v1.y = p[5];
                        if (kb + 6 < Kreal) v1.z = p[6];
                        if (kb + 7 < Kreal) v1.w = p[7];
                    }
                }
                aF[2 * i] = v0; aF[2 * i + 1] = v1;
            }
        } else {
            int t = k0 / 320, d0 = k0 - t * 320;
#pragma unroll
            for (int i = 0; i < 4; ++i) {
                int j = tid + i * 256;
                int r = j >> 3, kg = j & 7;
                int gr = row0 + r;
                ushort8v z = {0, 0, 0, 0, 0, 0, 0, 0};
                float aw = 0.0f;
                if (gr < M) {
                    z = *reinterpret_cast<const ushort8v*>(
                        Apre + ((size_t)t * BB + gr) * 320 + d0 + kg * 8);
                    aw = attnp[t * BB + gr];
                }
                aP[i] = z; aW[i] = aw;
            }
        }
    };
    auto loadB = [&](int c) {
        int k0 = c * 64;
#pragma unroll
        for (int i = 0; i < 4; ++i) {
            int j = tid + i * 256;
            int r = j >> 3, sg = j & 7;
            int gc = col0 + r;
            ushort8v z = {0, 0, 0, 0, 0, 0, 0, 0};
            if (gc < N) z = *reinterpret_cast<const ushort8v*>(Bn + (size_t)gc * ldb + k0 + sg * 8);
            bP[i] = z;
        }
    };
    auto writeAB = [&]() {
        if (VAR == 0) {
#pragma unroll
            for (int i = 0; i < 8; ++i) {
                int j = tid + i * 256;
                int r = j >> 4, cg = j & 15;
                *reinterpret_cast<ushort8v*>(&Al[r][cg * 8]) = aP[i];
            }
        } else {
#pragma unroll
            for (int i = 0; i < 4; ++i) {
                int j = tid + i * 256;
                int r = j >> 3, kg = j & 7;
                float f[8];
                if (VAR == 1) {
                    f[0] = aF[2 * i].x; f[1] = aF[2 * i].y; f[2] = aF[2 * i].z; f[3] = aF[2 * i].w;
                    f[4] = aF[2 * i + 1].x; f[5] = aF[2 * i + 1].y; f[6] = aF[2 * i + 1].z; f[7] = aF[2 * i + 1].w;
                } else {
#pragma unroll
                    for (int e = 0; e < 8; ++e) f[e] = bf2f(aP[i][e]) * aW[i];
                }
                ushort8v hv, lv;
#pragma unroll
                for (int e = 0; e < 8; ++e) {
                    unsigned hh, ll;
                    split3(f[e], hh, ll);
                    hv[e] = (unsigned short)hh; lv[e] = (unsigned short)ll;
                }
                *reinterpret_cast<ushort8v*>(&Al[r][kg * 8]) = hv;
                *reinterpret_cast<ushort8v*>(&Al[r][64 + kg * 8]) = lv;
            }
        }
#pragma unroll
        for (int i = 0; i < 4; ++i) {
            int j = tid + i * 256;
            int r = j >> 3, sg = j & 7;
            *reinterpret_cast<ushort8v*>(&Bl[r][sg * 8]) = bP[i];
        }
    };

    loadA(c_beg); loadB(c_beg);

    for (int c = c_beg; c < c_end; ++c) {
        __syncthreads();
        writeAB();
        __syncthreads();
        if (c + 1 < c_end) { loadA(c + 1); loadB(c + 1); }

#pragma unroll
        for (int ks = 0; ks < 2; ++ks) {
            short8v bf[4];
#pragma unroll
            for (int n = 0; n < 4; ++n)
                bf[n] = *reinterpret_cast<const short8v*>(&Bl[wc * 64 + n * 16 + l15][ks * 32 + lq * 8]);
#pragma unroll
            for (int pass = 0; pass < 2; ++pass) {
                short8v af[4];
#pragma unroll
                for (int m = 0; m < 4; ++m)
                    af[m] = *reinterpret_cast<const short8v*>(
                        &Al[wr * 64 + m * 16 + l15][pass * 64 + ks * 32 + lq * 8]);
#pragma unroll
                for (int m = 0; m < 4; ++m)
#pragma unroll
                    for (int n = 0; n < 4; ++n)
                        acc[m][n] = __builtin_amdgcn_mfma_f32_16x16x32_bf16(af[m], bf[n], acc[m][n], 0, 0, 0);
            }
        }
    }

    if (VAR != 0) {
#pragma unroll
        for (int m = 0; m < 4; ++m)
#pragma unroll
            for (int n = 0; n < 4; ++n)
#pragma unroll
                for (int rg = 0; rg < 4; ++rg) {
                    int row_g = row0 + wr * 64 + m * 16 + lq * 4 + rg;
                    int col_g = col0 + wc * 64 + n * 16 + l15;
                    if (row_g < M && col_g < N)
                        outp[((size_t)sp * M + row_g) * N + col_g] = acc[m][n][rg];
                }
    } else {
        int c0 = col0 + wc * 64;
        int dir = c0 / 640;
        int jgl = (c0 % 640) >> 6;
        int hcol = dir * HID + jgl * 16 + l15;
        float bi = biasv[c0 + l15];
        float bg = biasv[c0 + 32 + l15];
        float bo = biasv[c0 + 48 + l15];
#pragma unroll
        for (int m = 0; m < 4; ++m)
#pragma unroll
            for (int rg = 0; rg < 4; ++rg) {
                int row_g = row0 + wr * 64 + m * 16 + lq * 4 + rg;
                if (row_g >= M) continue;
                float gi = acc[m][0][rg] + bi;
                float gg = acc[m][2][rg] + bg;
                float go = acc[m][3][rg] + bo;
                float cc = sigf(gi) * tanhf(gg);
                hout[(size_t)row_g * 320 + hcol] = bf16rne(sigf(go) * tanhf(cc));
            }
    }
}

// ---------------------------------------------------------------------------
__global__ void gene_reduce_kernel(const float* __restrict__ part, const float* __restrict__ gene_b,
                                   float* __restrict__ out) {
    int idx = blockIdx.x * 256 + threadIdx.x;
    if (idx >= BB * GENE_N) return;
    int n = idx % GENE_N;
    float sum = gene_b[n];
#pragma unroll
    for (int ss = 0; ss < GENE_SPLITS; ++ss) sum += part[(size_t)ss * (BB * GENE_N) + idx];
    out[idx] = sum;
}

__global__ void bn_stats_kernel(const float* __restrict__ g, float* __restrict__ stats) {
    int n = blockIdx.x;
    int tid = threadIdx.x;
    float s = 0.0f, s2 = 0.0f;
    for (int m = tid; m < BB; m += 256) {
        float v = g[(size_t)m * GENE_N + n];
        s += v; s2 += v * v;
    }
    __shared__ float red0[256], red1[256];
    red0[tid] = s; red1[tid] = s2;
    __syncthreads();
    for (int off = 128; off; off >>= 1) {
        if (tid < off) { red0[tid] += red0[tid + off]; red1[tid] += red1[tid + off]; }
        __syncthreads();
    }
    if (tid == 0) {
        float mean = red0[0] / (float)BB;
        float var = red1[0] / (float)BB - mean * mean;
        stats[n] = mean;
        stats[GENE_N + n] = rsqrtf(var + 1e-5f);
    }
}

// attn with BN-normalize + ReLU fused (gene consumed only here).
// 4 rows per 256-thread block; one wave per row.
__global__ void attn_kernel(const unsigned short* __restrict__ h, const float* __restrict__ graw,
                            const float* __restrict__ stats,
                            const float* __restrict__ gamma, const float* __restrict__ beta,
                            float* __restrict__ attn) {
    int r = blockIdx.x * 4 + (threadIdx.x >> 6);
    int b = r % BB;
    int lane = threadIdx.x & 63;
    const unsigned short* hr = h + (size_t)r * 320;
    const float* gr = graw + (size_t)b * 320;
    float s = 0.0f;
    for (int d = lane; d < 320; d += 64) {
        float gv = (gr[d] - stats[d]) * stats[GENE_N + d] * gamma[d] + beta[d];
        gv = fmaxf(gv, 0.0f);
        s += bf2f(hr[d]) * gv;
    }
    for (int off = 32; off; off >>= 1) s += __shfl_down(s, off);
    if (lane == 0) attn[r] = s;
}

__global__ void lin_reduce_kernel(const float* __restrict__ part, const float* __restrict__ lin_b,
                                  float* __restrict__ hid) {
    int idx = blockIdx.x * 256 + threadIdx.x;
    if (idx >= BB * LIN_N) return;
    int n = idx % LIN_N;
    float sum = lin_b[n];
#pragma unroll
    for (int ss = 0; ss < LIN_SPLITS; ++ss) sum += part[(size_t)ss * (BB * LIN_N) + idx];
    hid[idx] = fmaxf(sum, 0.0f);
}

__global__ void out_kernel(const float* __restrict__ hid, const float* __restrict__ ow,
                           const float* __restrict__ ob, float* __restrict__ out) {
    int b = blockIdx.x;
    int lane = threadIdx.x;
    float s = 0.0f;
    for (int n = lane; n < LIN_N; n += 64) s += hid[(size_t)b * LIN_N + n] * ow[n];
    for (int off = 32; off; off >>= 1) s += __shfl_down(s, off);
    if (lane == 0) out[b] = s + ob[0];
}

// ---------------------------------------------------------------------------
extern "C" void kernel_launch(void* const* d_in, const int* in_sizes, int n_in,
                              void* d_out, int out_size, void* d_ws, size_t ws_size,
                              hipStream_t stream) {
    const float* x        = (const float*)d_in[0];
    const float* geneexpr = (const float*)d_in[1];
    const float* conv_w   = (const float*)d_in[2];
    const float* conv_b   = (const float*)d_in[3];
    const float* w_ih_f   = (const float*)d_in[4];
    const float* b_ih_f   = (const float*)d_in[5];
    const float* b_hh_f   = (const float*)d_in[6];
    const float* w_ih_b   = (const float*)d_in[7];
    const float* b_ih_b   = (const float*)d_in[8];
    const float* b_hh_b   = (const float*)d_in[9];
    const float* gene_w   = (const float*)d_in[10];
    const float* gene_b   = (const float*)d_in[11];
    const float* bn_gamma = (const float*)d_in[12];
    const float* bn_beta  = (const float*)d_in[13];
    const float* lin_w    = (const float*)d_in[14];
    const float* lin_b    = (const float*)d_in[15];
    const float* out_w    = (const float*)d_in[16];
    const float* out_b    = (const float*)d_in[17];

    float* ws  = (float*)d_ws;
    float* out = (float*)d_out;

    unsigned short* seqs  = (unsigned short*)(ws + OFF_SEQS);
    unsigned short* h     = (unsigned short*)(ws + OFF_H);
    unsigned short* Bp    = (unsigned short*)(ws + OFF_BP);
    float* biasv          = ws + OFF_BIAS;
    unsigned short* wd    = (unsigned short*)(ws + OFF_WD);
    unsigned short* genew = (unsigned short*)(ws + OFF_GENEW);
    unsigned short* linw  = (unsigned short*)(ws + OFF_LINW);
    float* gene           = ws + OFF_GENE;
    float* stats          = ws + OFF_STATS;
    float* attn           = ws + OFF_ATTN;
    float* hid            = ws + OFF_HID;
    float* gpart          = ws + OFF_SEQS;  // alias: seqs dead after LSTM GEMM
    float* lpart          = ws + OFF_SEQS;  // alias: gpart dead after gene_reduce

    // 1. weight preps (bf16)
    prep_lstm_kernel<<<1600, 256, 0, stream>>>(w_ih_f, b_ih_f, b_hh_f,
                                               w_ih_b, b_ih_b, b_hh_b, Bp, biasv);
    prep_convw_kernel<<<160, 256, 0, stream>>>(conv_w, wd);
    prep_genew_kernel<<<24800, 256, 0, stream>>>(gene_w, genew);
    prep_linw_kernel<<<52032, 256, 0, stream>>>(lin_w, linw);
    // 2. fused conv -> seqs (pre-split hi|lo)
    conv_mfma_kernel<<<dim3(BB * 5, 3, 1), 256, 0, stream>>>(x, wd, conv_b, seqs);
    // 3. LSTM GEMM (XCD-pinned bm, bn-fastest) -> h bf16
    gemm2<0><<<dim3(8, 360), 256, 0, stream>>>(
        seqs, nullptr, 0, Bp, LSTM_K, nullptr,
        LSTM_M, LSTM_N, LSTM_K, 5, 5, nullptr, biasv, h);
    // 4. gene GEMM (split-K 16, XCD-pinned sp)
    gemm2<1><<<dim3(8, 42), 256, 0, stream>>>(
        nullptr, geneexpr, GENE_K, genew, GENE_KP, nullptr,
        BB, GENE_N, GENE_K, 310, 20, gpart, nullptr, nullptr);
    // 5. reduce + bias
    gene_reduce_kernel<<<1000, 256, 0, stream>>>(gpart, gene_b, gene);
    // 6. BN stats
    bn_stats_kernel<<<GENE_N, 256, 0, stream>>>(gene, stats);
    // 7. attention scores (BN apply fused)
    attn_kernel<<<9000, 256, 0, stream>>>(h, gene, stats, bn_gamma, bn_beta, attn);
    // 8. lin GEMM (split-K 8 = XCD, A = attn*h on the fly)
    gemm2<2><<<dim3(8, 56), 256, 0, stream>>>(
        h, nullptr, 0, linw, LIN_K, attn,
        BB, LIN_N, LIN_K, 225, 29, lpart, nullptr, nullptr);
    // 9. reduce + bias + relu
    lin_reduce_kernel<<<2891, 256, 0, stream>>>(lpart, lin_b, hid);
    // 10. final dot
    out_kernel<<<BB, 64, 0, stream>>>(hid, out_w, out_b, out);
}